// Round 1
// baseline (767.790 us; speedup 1.0000x reference)
//
#include <hip/hip_runtime.h>
#include <math.h>

#define Hdim 1024
#define VOC 32000
#define LSEQ 128
#define BSZ 64

__device__ __forceinline__ float fast_tanhf(float x) {
    // tanh(x) = 1 - 2/(exp(2x)+1); __expf handles +-inf limits correctly
    return 1.0f - 2.0f / (__expf(2.0f * x) + 1.0f);
}
__device__ __forceinline__ float sigmoidf(float x) {
    return 1.0f / (1.0f + __expf(-x));
}

// ---------------------------------------------------------------------------
// Generic C = A @ B^T + bias   (TN GEMM, all f32)
// A: [M, K] row-major, lda; B: [N, K] row-major, ldb; C: [M, N] row-major, ldc
// tile 64x64, BK=16, 256 threads, 4x4 micro-tile per thread.
// grid = (N/64, M/64); M, N, K all multiples of tile dims (true for all uses).
// ---------------------------------------------------------------------------
__global__ __launch_bounds__(256) void gemm_tn(
    const float* __restrict__ A, int lda,
    const float* __restrict__ B, int ldb,
    const float* __restrict__ bias,
    float* __restrict__ C, int ldc,
    int K)
{
    __shared__ float As[16][68];  // [k][m], pad to 68 to keep 16B alignment
    __shared__ float Bs[16][68];  // [k][n]

    const int m0 = blockIdx.y * 64;
    const int n0 = blockIdx.x * 64;
    const int tid = threadIdx.x;
    const int tx = tid & 15, ty = tid >> 4;
    const int lrow = tid >> 2;            // 0..63
    const int lkq  = (tid & 3) * 4;       // 0,4,8,12

    float acc[4][4] = {};

    for (int k0 = 0; k0 < K; k0 += 16) {
        float4 va = *(const float4*)(A + (size_t)(m0 + lrow) * lda + k0 + lkq);
        float4 vb = *(const float4*)(B + (size_t)(n0 + lrow) * ldb + k0 + lkq);
        As[lkq + 0][lrow] = va.x; As[lkq + 1][lrow] = va.y;
        As[lkq + 2][lrow] = va.z; As[lkq + 3][lrow] = va.w;
        Bs[lkq + 0][lrow] = vb.x; Bs[lkq + 1][lrow] = vb.y;
        Bs[lkq + 2][lrow] = vb.z; Bs[lkq + 3][lrow] = vb.w;
        __syncthreads();
#pragma unroll
        for (int kk = 0; kk < 16; ++kk) {
            float4 av = *(const float4*)&As[kk][ty * 4];
            float4 bv = *(const float4*)&Bs[kk][tx * 4];
            float a[4] = {av.x, av.y, av.z, av.w};
            float b[4] = {bv.x, bv.y, bv.z, bv.w};
#pragma unroll
            for (int i = 0; i < 4; ++i)
#pragma unroll
                for (int j = 0; j < 4; ++j)
                    acc[i][j] = fmaf(a[i], b[j], acc[i][j]);
        }
        __syncthreads();
    }

    float4 bv = *(const float4*)&bias[n0 + tx * 4];
    float bb[4] = {bv.x, bv.y, bv.z, bv.w};
#pragma unroll
    for (int i = 0; i < 4; ++i) {
        float4 o;
        o.x = acc[i][0] + bb[0];
        o.y = acc[i][1] + bb[1];
        o.z = acc[i][2] + bb[2];
        o.w = acc[i][3] + bb[3];
        *(float4*)(C + (size_t)(m0 + ty * 4 + i) * ldc + n0 + tx * 4) = o;
    }
}

// ---------------------------------------------------------------------------
// Fused attention scores:
// scores_part[g][l*64+b] = sum_{h in group g} v[h]*tanh( enc[l*B+b,:]·W1[h,:] + u[b,h] )
// One block per (l, h-group); h-group = 256 h values = 4 tiles of 64.
// ---------------------------------------------------------------------------
__global__ __launch_bounds__(256) void attn_scores(
    const float* __restrict__ enc,    // [L*B, H] row-major (m = l*B+b)
    const float* __restrict__ W1,     // attn_W, use cols [0,H), ld = 2H
    const float* __restrict__ u,      // [B, H]
    const float* __restrict__ vvec,   // [H]
    float* __restrict__ scores_part)  // [4][L*B]
{
    __shared__ float As[16][68];
    __shared__ float Bs[16][68];
    __shared__ float sred[64][17];

    const int l = blockIdx.x;         // 0..127
    const int g = blockIdx.y;         // 0..3
    const int m0 = l * 64;
    const int tid = threadIdx.x;
    const int tx = tid & 15, ty = tid >> 4;
    const int lrow = tid >> 2;
    const int lkq  = (tid & 3) * 4;

    float ssum = 0.0f;                // valid for tid < 64

    for (int ht = 0; ht < 4; ++ht) {
        const int h0 = g * 256 + ht * 64;
        float acc[4][4] = {};
        for (int k0 = 0; k0 < Hdim; k0 += 16) {
            float4 va = *(const float4*)(enc + (size_t)(m0 + lrow) * Hdim + k0 + lkq);
            float4 vb = *(const float4*)(W1 + (size_t)(h0 + lrow) * (2 * Hdim) + k0 + lkq);
            As[lkq + 0][lrow] = va.x; As[lkq + 1][lrow] = va.y;
            As[lkq + 2][lrow] = va.z; As[lkq + 3][lrow] = va.w;
            Bs[lkq + 0][lrow] = vb.x; Bs[lkq + 1][lrow] = vb.y;
            Bs[lkq + 2][lrow] = vb.z; Bs[lkq + 3][lrow] = vb.w;
            __syncthreads();
#pragma unroll
            for (int kk = 0; kk < 16; ++kk) {
                float4 av = *(const float4*)&As[kk][ty * 4];
                float4 bv = *(const float4*)&Bs[kk][tx * 4];
                float a[4] = {av.x, av.y, av.z, av.w};
                float b[4] = {bv.x, bv.y, bv.z, bv.w};
#pragma unroll
                for (int i = 0; i < 4; ++i)
#pragma unroll
                    for (int j = 0; j < 4; ++j)
                        acc[i][j] = fmaf(a[i], b[j], acc[i][j]);
            }
            __syncthreads();
        }
        // epilogue: p_i = sum_j v[h]*tanh(acc + u[b,h]);  b = ty*4+i, h = h0+tx*4+j
        float4 vv = *(const float4*)&vvec[h0 + tx * 4];
        float vr[4] = {vv.x, vv.y, vv.z, vv.w};
#pragma unroll
        for (int i = 0; i < 4; ++i) {
            const int b = ty * 4 + i;
            float4 uu = *(const float4*)(u + (size_t)b * Hdim + h0 + tx * 4);
            float ur[4] = {uu.x, uu.y, uu.z, uu.w};
            float p = 0.0f;
#pragma unroll
            for (int j = 0; j < 4; ++j)
                p += vr[j] * fast_tanhf(acc[i][j] + ur[j]);
            sred[b][tx] = p;
        }
        __syncthreads();
        if (tid < 64) {
            float s = 0.0f;
#pragma unroll
            for (int t = 0; t < 16; ++t) s += sred[tid][t];
            ssum += s;
        }
        __syncthreads();
    }
    if (tid < 64)
        scores_part[(size_t)g * (LSEQ * BSZ) + (size_t)l * 64 + tid] = ssum;
}

// ---------------------------------------------------------------------------
// Softmax over L per batch row; block = one b, 128 threads (one per l).
// ---------------------------------------------------------------------------
__global__ __launch_bounds__(128) void softmax_attn(
    const float* __restrict__ scores_part,  // [4][L*B]
    float* __restrict__ attn_out)           // [B, L]
{
    const int b = blockIdx.x;
    const int l = threadIdx.x;
    float s = 0.0f;
#pragma unroll
    for (int g = 0; g < 4; ++g) s += scores_part[g * (LSEQ * BSZ) + l * 64 + b];

    __shared__ float red[128];
    red[l] = s;
    __syncthreads();
    for (int off = 64; off > 0; off >>= 1) {
        if (l < off) red[l] = fmaxf(red[l], red[l + off]);
        __syncthreads();
    }
    const float mx = red[0];
    __syncthreads();
    const float e = __expf(s - mx);
    red[l] = e;
    __syncthreads();
    for (int off = 64; off > 0; off >>= 1) {
        if (l < off) red[l] += red[l + off];
        __syncthreads();
    }
    attn_out[(size_t)b * LSEQ + l] = e / red[0];
}

// ---------------------------------------------------------------------------
// weighted[b,h] = sum_l attn[b,l]*enc[l*B+b, h]; writes into x[:,H:2H] and
// out_cat[:,H:2H].
// ---------------------------------------------------------------------------
__global__ __launch_bounds__(256) void weighted_kernel(
    const float* __restrict__ enc,
    const float* __restrict__ attn,   // [B, L]
    float* __restrict__ x,            // [B, 2H]
    float* __restrict__ outcat)       // [B, 3H]
{
    const int idx = blockIdx.x * 256 + threadIdx.x;  // B*H threads
    const int b = idx >> 10, h = idx & 1023;
    float acc = 0.0f;
    for (int l = 0; l < LSEQ; ++l)
        acc = fmaf(attn[b * LSEQ + l], enc[((size_t)l * BSZ + b) * Hdim + h], acc);
    x[(size_t)b * (2 * Hdim) + Hdim + h] = acc;
    outcat[(size_t)b * (3 * Hdim) + Hdim + h] = acc;
}

// ---------------------------------------------------------------------------
// embedding gather: x[:,0:H] and out_cat[:,2H:3H]
// ---------------------------------------------------------------------------
__global__ __launch_bounds__(256) void embed_kernel(
    const int* __restrict__ ids,
    const float* __restrict__ emb,
    float* __restrict__ x,
    float* __restrict__ outcat)
{
    const int idx = blockIdx.x * 256 + threadIdx.x;
    const int b = idx >> 10, h = idx & 1023;
    const float e = emb[(size_t)ids[b] * Hdim + h];
    x[(size_t)b * (2 * Hdim) + h] = e;
    outcat[(size_t)b * (3 * Hdim) + 2 * Hdim + h] = e;
}

// ---------------------------------------------------------------------------
// GRU elementwise: h_new from gx, gh, h0; writes d_out h_new and out_cat[:,0:H]
// ---------------------------------------------------------------------------
__global__ __launch_bounds__(256) void gru_kernel(
    const float* __restrict__ gx,     // [B, 3H]
    const float* __restrict__ gh,     // [B, 3H]
    const float* __restrict__ h0,     // [B, H]
    float* __restrict__ hnew_out,     // [B, H]  (d_out)
    float* __restrict__ outcat)       // [B, 3H]
{
    const int idx = blockIdx.x * 256 + threadIdx.x;
    const int b = idx >> 10, h = idx & 1023;
    const size_t g3 = (size_t)b * (3 * Hdim);
    const float xr = gx[g3 + h], xz = gx[g3 + Hdim + h], xn = gx[g3 + 2 * Hdim + h];
    const float hr = gh[g3 + h], hz = gh[g3 + Hdim + h], hn = gh[g3 + 2 * Hdim + h];
    const float r = sigmoidf(xr + hr);
    const float z = sigmoidf(xz + hz);
    const float n = fast_tanhf(xn + r * hn);
    const float hv = (1.0f - z) * n + z * h0[(size_t)b * Hdim + h];
    hnew_out[(size_t)b * Hdim + h] = hv;
    outcat[g3 + h] = hv;
}

// ---------------------------------------------------------------------------
extern "C" void kernel_launch(void* const* d_in, const int* in_sizes, int n_in,
                              void* d_out, int out_size, void* d_ws, size_t ws_size,
                              hipStream_t stream)
{
    const int*   ids    = (const int*)d_in[0];
    const float* hidden = (const float*)d_in[1];   // [B, H]
    const float* enc    = (const float*)d_in[2];   // [L, B, H]
    const float* emb    = (const float*)d_in[3];   // [VOC, H]
    const float* attnW  = (const float*)d_in[4];   // [H, 2H]
    const float* attnb  = (const float*)d_in[5];   // [H]
    const float* vvec   = (const float*)d_in[6];   // [H]
    const float* w_ih   = (const float*)d_in[7];   // [3H, 2H]
    const float* w_hh   = (const float*)d_in[8];   // [3H, H]
    const float* b_ih   = (const float*)d_in[9];   // [3H]
    const float* b_hh   = (const float*)d_in[10];  // [3H]
    const float* out_W  = (const float*)d_in[11];  // [VOC, 3H]
    const float* out_b  = (const float*)d_in[12];  // [VOC]

    float* out        = (float*)d_out;
    float* out_logits = out;                         // [B, VOC]
    float* out_hnew   = out + (size_t)BSZ * VOC;     // [B, H]
    float* out_attn   = out_hnew + (size_t)BSZ * Hdim; // [B, L]

    float* ws    = (float*)d_ws;
    float* ws_u  = ws;                       // B*H      = 65536
    float* ws_sp = ws_u + BSZ * Hdim;        // 4*L*B    = 32768
    float* ws_x  = ws_sp + 4 * LSEQ * BSZ;   // B*2H     = 131072
    float* ws_gx = ws_x + BSZ * 2 * Hdim;    // B*3H     = 196608
    float* ws_gh = ws_gx + BSZ * 3 * Hdim;   // B*3H     = 196608
    float* ws_oc = ws_gh + BSZ * 3 * Hdim;   // B*3H     = 196608

    // 1. u = h0 @ W2^T + attn_b   [B, H]
    gemm_tn<<<dim3(Hdim / 64, 1), 256, 0, stream>>>(
        hidden, Hdim, attnW + Hdim, 2 * Hdim, attnb, ws_u, Hdim, Hdim);

    // 2. embedding gather (independent)
    embed_kernel<<<dim3(BSZ * Hdim / 256), 256, 0, stream>>>(ids, emb, ws_x, ws_oc);

    // 3. fused energy GEMM + tanh + v-reduction -> score partials
    attn_scores<<<dim3(LSEQ, 4), 256, 0, stream>>>(enc, attnW, ws_u, vvec, ws_sp);

    // 4. softmax over L -> attention (final output region)
    softmax_attn<<<dim3(BSZ), 128, 0, stream>>>(ws_sp, out_attn);

    // 5. weighted context
    weighted_kernel<<<dim3(BSZ * Hdim / 256), 256, 0, stream>>>(enc, out_attn, ws_x, ws_oc);

    // 6. GRU gate GEMMs
    gemm_tn<<<dim3(3 * Hdim / 64, 1), 256, 0, stream>>>(
        ws_x, 2 * Hdim, w_ih, 2 * Hdim, b_ih, ws_gx, 3 * Hdim, 2 * Hdim);
    gemm_tn<<<dim3(3 * Hdim / 64, 1), 256, 0, stream>>>(
        hidden, Hdim, w_hh, Hdim, b_hh, ws_gh, 3 * Hdim, Hdim);

    // 7. GRU elementwise -> h_new (output) + out_cat[:,0:H]
    gru_kernel<<<dim3(BSZ * Hdim / 256), 256, 0, stream>>>(
        ws_gx, ws_gh, hidden, out_hnew, ws_oc);

    // 8. output projection [B, VOC]
    gemm_tn<<<dim3(VOC / 64, 1), 256, 0, stream>>>(
        ws_oc, 3 * Hdim, out_W, 3 * Hdim, out_b, out_logits, VOC, 3 * Hdim);
}

// Round 2
// 286.101 us; speedup vs baseline: 2.6836x; 2.6836x over previous
//
#include <hip/hip_runtime.h>
#include <math.h>

#define Hdim 1024
#define VOC 32000
#define LSEQ 128
#define BSZ 64

typedef __attribute__((ext_vector_type(8))) short bf16x8;
typedef __attribute__((ext_vector_type(4))) float f32x4;

__device__ __forceinline__ float fast_tanhf(float x) {
    return 1.0f - 2.0f / (__expf(2.0f * x) + 1.0f);
}
__device__ __forceinline__ float sigmoidf(float x) {
    return 1.0f / (1.0f + __expf(-x));
}
__device__ __forceinline__ short f2bf(float f) {
    unsigned u = __float_as_uint(f);
    unsigned r = (u + 0x7fffu + ((u >> 16) & 1u)) >> 16;
    return (short)r;
}

// load 16 consecutive f32 from src, convert to bf16, store to LDS dst (2x b128)
__device__ __forceinline__ void stage16(const float* __restrict__ src, short* dst) {
    f32x4 v0 = *(const f32x4*)(src);
    f32x4 v1 = *(const f32x4*)(src + 4);
    f32x4 v2 = *(const f32x4*)(src + 8);
    f32x4 v3 = *(const f32x4*)(src + 12);
    bf16x8 p0, p1;
    p0[0] = f2bf(v0[0]); p0[1] = f2bf(v0[1]); p0[2] = f2bf(v0[2]); p0[3] = f2bf(v0[3]);
    p0[4] = f2bf(v1[0]); p0[5] = f2bf(v1[1]); p0[6] = f2bf(v1[2]); p0[7] = f2bf(v1[3]);
    p1[0] = f2bf(v2[0]); p1[1] = f2bf(v2[1]); p1[2] = f2bf(v2[2]); p1[3] = f2bf(v2[3]);
    p1[4] = f2bf(v3[0]); p1[5] = f2bf(v3[1]); p1[6] = f2bf(v3[2]); p1[7] = f2bf(v3[3]);
    *(bf16x8*)(dst) = p0;
    *(bf16x8*)(dst + 8) = p1;
}

// ---------------------------------------------------------------------------
// Generic bf16-MFMA TN GEMM: C = A(f32)[64,K] @ B(f32)[N,K]^T (+bias)
// Tile: BM=64 (all of M), BN=128, BK=64. 256 threads = 4 waves, each wave a
// 64x32 slab (4x2 fragments of 16x16x32).
// grid = (N/128, splitk); block s handles k in [s*klen, (s+1)*klen),
// writing to C + s*part_stride (no bias for partials).
// ---------------------------------------------------------------------------
__global__ __launch_bounds__(256) void gemm_bt_bf16(
    const float* __restrict__ A, int lda,
    const float* __restrict__ B, int ldb,
    const float* __restrict__ bias,
    float* __restrict__ C, int ldc, size_t part_stride,
    int klen)
{
    __shared__ short As[64 * 72];   // pad rows to 72 bf16 (144 B) -> 2-way banks
    __shared__ short Bs[128 * 72];

    const int t = threadIdx.x;
    const int lane = t & 63, wave = t >> 6;
    const int lr = lane & 15, kh = lane >> 4;
    const int n0 = blockIdx.x * 128;
    const int kstart = blockIdx.y * klen;
    float* Cp = C + (size_t)blockIdx.y * part_stride;

    const int ar = t >> 2, ac = (t & 3) * 16;   // A: 64 rows x 64 cols
    const int br = t >> 1, bc = (t & 1) * 32;   // B: 128 rows x 64 cols

    f32x4 acc[4][2] = {};

    for (int k0 = 0; k0 < klen; k0 += 64) {
        const int kg = kstart + k0;
        stage16(A + (size_t)ar * lda + kg + ac, As + ar * 72 + ac);
        stage16(B + (size_t)(n0 + br) * ldb + kg + bc,      Bs + br * 72 + bc);
        stage16(B + (size_t)(n0 + br) * ldb + kg + bc + 16, Bs + br * 72 + bc + 16);
        __syncthreads();
#pragma unroll
        for (int kk = 0; kk < 64; kk += 32) {
            bf16x8 af[4], bfr[2];
#pragma unroll
            for (int mi = 0; mi < 4; ++mi)
                af[mi] = *(const bf16x8*)(As + (mi * 16 + lr) * 72 + kk + kh * 8);
#pragma unroll
            for (int ni = 0; ni < 2; ++ni)
                bfr[ni] = *(const bf16x8*)(Bs + (wave * 32 + ni * 16 + lr) * 72 + kk + kh * 8);
#pragma unroll
            for (int mi = 0; mi < 4; ++mi)
#pragma unroll
                for (int ni = 0; ni < 2; ++ni)
                    acc[mi][ni] = __builtin_amdgcn_mfma_f32_16x16x32_bf16(
                        af[mi], bfr[ni], acc[mi][ni], 0, 0, 0);
        }
        __syncthreads();
    }

    const bool has_bias = (bias != nullptr);
#pragma unroll
    for (int mi = 0; mi < 4; ++mi)
#pragma unroll
        for (int ni = 0; ni < 2; ++ni) {
            const int col = n0 + wave * 32 + ni * 16 + lr;
            const float bb = has_bias ? bias[col] : 0.0f;
#pragma unroll
            for (int r = 0; r < 4; ++r) {
                const int row = mi * 16 + kh * 4 + r;
                Cp[(size_t)row * ldc + col] = acc[mi][ni][r] + bb;
            }
        }
}

// ---------------------------------------------------------------------------
// Fused attention scores (bf16 MFMA):
// energy[m,h] = enc[m,:] . W1[h,:]   (m = l*64+b, K = 1024)
// partial[g][m] = sum_{h in 128-col group g} v[h]*tanh(energy + u[b,h])
// u already contains W2.h0 + attn_b. grid = (128 m-tiles, 8 col-groups).
// ---------------------------------------------------------------------------
__global__ __launch_bounds__(256) void attn_scores_mfma(
    const float* __restrict__ enc,   // [8192, 1024]
    const float* __restrict__ W1,    // attn_W, ld 2048, cols [0,1024)
    const float* __restrict__ u,     // [64, 1024]
    const float* __restrict__ vvec,  // [1024]
    float* __restrict__ scores_part) // [8][8192]
{
    __shared__ short As[64 * 72];
    __shared__ short Bs[128 * 72];
    __shared__ float red[4][64];

    const int t = threadIdx.x;
    const int lane = t & 63, wave = t >> 6;
    const int lr = lane & 15, kh = lane >> 4;
    const int m0 = blockIdx.x * 64;
    const int n0 = blockIdx.y * 128;

    const int ar = t >> 2, ac = (t & 3) * 16;
    const int br = t >> 1, bc = (t & 1) * 32;

    f32x4 acc[4][2] = {};

    for (int kg = 0; kg < Hdim; kg += 64) {
        stage16(enc + (size_t)(m0 + ar) * Hdim + kg + ac, As + ar * 72 + ac);
        stage16(W1 + (size_t)(n0 + br) * (2 * Hdim) + kg + bc,      Bs + br * 72 + bc);
        stage16(W1 + (size_t)(n0 + br) * (2 * Hdim) + kg + bc + 16, Bs + br * 72 + bc + 16);
        __syncthreads();
#pragma unroll
        for (int kk = 0; kk < 64; kk += 32) {
            bf16x8 af[4], bfr[2];
#pragma unroll
            for (int mi = 0; mi < 4; ++mi)
                af[mi] = *(const bf16x8*)(As + (mi * 16 + lr) * 72 + kk + kh * 8);
#pragma unroll
            for (int ni = 0; ni < 2; ++ni)
                bfr[ni] = *(const bf16x8*)(Bs + (wave * 32 + ni * 16 + lr) * 72 + kk + kh * 8);
#pragma unroll
            for (int mi = 0; mi < 4; ++mi)
#pragma unroll
                for (int ni = 0; ni < 2; ++ni)
                    acc[mi][ni] = __builtin_amdgcn_mfma_f32_16x16x32_bf16(
                        af[mi], bfr[ni], acc[mi][ni], 0, 0, 0);
        }
        __syncthreads();
    }

    // epilogue: tanh + v-weight + reduce over the block's 128 cols
    float sv[16];
#pragma unroll
    for (int mi = 0; mi < 4; ++mi)
#pragma unroll
        for (int r = 0; r < 4; ++r) {
            const int row = mi * 16 + kh * 4 + r;   // local m; b = row (m0 % 64 == 0)
            float s = 0.0f;
#pragma unroll
            for (int ni = 0; ni < 2; ++ni) {
                const int h = n0 + wave * 32 + ni * 16 + lr;
                const float e = fast_tanhf(acc[mi][ni][r] + u[(size_t)row * Hdim + h]);
                s += e * vvec[h];
            }
            sv[mi * 4 + r] = s;
        }
    // reduce across the 16 lanes sharing the same rows (lane bits 0-3)
#pragma unroll
    for (int i = 0; i < 16; ++i) {
#pragma unroll
        for (int d = 1; d < 16; d <<= 1)
            sv[i] += __shfl_xor(sv[i], d, 64);
    }
    if (lr == 0) {
#pragma unroll
        for (int mi = 0; mi < 4; ++mi)
#pragma unroll
            for (int r = 0; r < 4; ++r)
                red[wave][mi * 16 + kh * 4 + r] = sv[mi * 4 + r];
    }
    __syncthreads();
    if (t < 64)
        scores_part[(size_t)blockIdx.y * (LSEQ * BSZ) + m0 + t] =
            red[0][t] + red[1][t] + red[2][t] + red[3][t];
}

// ---------------------------------------------------------------------------
// u = sum of 4 split-K partials + attn_b  (u[b,h], 65536 elems)
// ---------------------------------------------------------------------------
__global__ __launch_bounds__(256) void ucomb(
    const float* __restrict__ u4, const float* __restrict__ attnb,
    float* __restrict__ u)
{
    const int i = blockIdx.x * 256 + threadIdx.x;
    u[i] = u4[i] + u4[65536 + i] + u4[2 * 65536 + i] + u4[3 * 65536 + i]
         + attnb[i & 1023];
}

// ---------------------------------------------------------------------------
__global__ __launch_bounds__(128) void softmax_attn(
    const float* __restrict__ scores_part,  // [8][L*B]
    float* __restrict__ attn_out)           // [B, L]
{
    const int b = blockIdx.x;
    const int l = threadIdx.x;
    float s = 0.0f;
#pragma unroll
    for (int g = 0; g < 8; ++g) s += scores_part[g * (LSEQ * BSZ) + l * 64 + b];

    __shared__ float red[128];
    red[l] = s;
    __syncthreads();
    for (int off = 64; off > 0; off >>= 1) {
        if (l < off) red[l] = fmaxf(red[l], red[l + off]);
        __syncthreads();
    }
    const float mx = red[0];
    __syncthreads();
    const float e = __expf(s - mx);
    red[l] = e;
    __syncthreads();
    for (int off = 64; off > 0; off >>= 1) {
        if (l < off) red[l] += red[l + off];
        __syncthreads();
    }
    attn_out[(size_t)b * LSEQ + l] = e / red[0];
}

// ---------------------------------------------------------------------------
__global__ __launch_bounds__(256) void weighted_kernel(
    const float* __restrict__ enc,
    const float* __restrict__ attn,   // [B, L]
    float* __restrict__ x,            // [B, 2H]
    float* __restrict__ outcat)       // [B, 3H]
{
    const int idx = blockIdx.x * 256 + threadIdx.x;
    const int b = idx >> 10, h = idx & 1023;
    float acc = 0.0f;
    for (int l = 0; l < LSEQ; ++l)
        acc = fmaf(attn[b * LSEQ + l], enc[((size_t)l * BSZ + b) * Hdim + h], acc);
    x[(size_t)b * (2 * Hdim) + Hdim + h] = acc;
    outcat[(size_t)b * (3 * Hdim) + Hdim + h] = acc;
}

// ---------------------------------------------------------------------------
__global__ __launch_bounds__(256) void embed_kernel(
    const int* __restrict__ ids,
    const float* __restrict__ emb,
    float* __restrict__ x,
    float* __restrict__ outcat)
{
    const int idx = blockIdx.x * 256 + threadIdx.x;
    const int b = idx >> 10, h = idx & 1023;
    const float e = emb[(size_t)ids[b] * Hdim + h];
    x[(size_t)b * (2 * Hdim) + h] = e;
    outcat[(size_t)b * (3 * Hdim) + 2 * Hdim + h] = e;
}

// ---------------------------------------------------------------------------
// GRU elementwise; sums 4 split-K partials of gx and gh + biases.
// ---------------------------------------------------------------------------
__global__ __launch_bounds__(256) void gru_kernel(
    const float* __restrict__ gx4,    // [4][B, 3H]
    const float* __restrict__ gh4,    // [4][B, 3H]
    const float* __restrict__ b_ih,
    const float* __restrict__ b_hh,
    const float* __restrict__ h0,     // [B, H]
    float* __restrict__ hnew_out,     // [B, H]
    float* __restrict__ outcat)       // [B, 3H]
{
    const int idx = blockIdx.x * 256 + threadIdx.x;
    const int b = idx >> 10, h = idx & 1023;
    const size_t g3 = (size_t)b * (3 * Hdim);
    const size_t P = (size_t)BSZ * 3 * Hdim;
    float xr = b_ih[h], xz = b_ih[Hdim + h], xn = b_ih[2 * Hdim + h];
    float hr = b_hh[h], hz = b_hh[Hdim + h], hn = b_hh[2 * Hdim + h];
#pragma unroll
    for (int s = 0; s < 4; ++s) {
        xr += gx4[s * P + g3 + h];
        xz += gx4[s * P + g3 + Hdim + h];
        xn += gx4[s * P + g3 + 2 * Hdim + h];
        hr += gh4[s * P + g3 + h];
        hz += gh4[s * P + g3 + Hdim + h];
        hn += gh4[s * P + g3 + 2 * Hdim + h];
    }
    const float r = sigmoidf(xr + hr);
    const float z = sigmoidf(xz + hz);
    const float n = fast_tanhf(xn + r * hn);
    const float hv = (1.0f - z) * n + z * h0[(size_t)b * Hdim + h];
    hnew_out[(size_t)b * Hdim + h] = hv;
    outcat[g3 + h] = hv;
}

// ---------------------------------------------------------------------------
extern "C" void kernel_launch(void* const* d_in, const int* in_sizes, int n_in,
                              void* d_out, int out_size, void* d_ws, size_t ws_size,
                              hipStream_t stream)
{
    const int*   ids    = (const int*)d_in[0];
    const float* hidden = (const float*)d_in[1];   // [B, H]
    const float* enc    = (const float*)d_in[2];   // [L, B, H]
    const float* emb    = (const float*)d_in[3];   // [VOC, H]
    const float* attnW  = (const float*)d_in[4];   // [H, 2H]
    const float* attnb  = (const float*)d_in[5];   // [H]
    const float* vvec   = (const float*)d_in[6];   // [H]
    const float* w_ih   = (const float*)d_in[7];   // [3H, 2H]
    const float* w_hh   = (const float*)d_in[8];   // [3H, H]
    const float* b_ih   = (const float*)d_in[9];   // [3H]
    const float* b_hh   = (const float*)d_in[10];  // [3H]
    const float* out_W  = (const float*)d_in[11];  // [VOC, 3H]
    const float* out_b  = (const float*)d_in[12];  // [VOC]

    float* out        = (float*)d_out;
    float* out_logits = out;                           // [B, VOC]
    float* out_hnew   = out + (size_t)BSZ * VOC;       // [B, H]
    float* out_attn   = out_hnew + (size_t)BSZ * Hdim; // [B, L]

    float* ws     = (float*)d_ws;
    float* ws_u4  = ws;                                  // 4*B*H    = 262144
    float* ws_u   = ws_u4 + 4 * BSZ * Hdim;              // B*H      = 65536
    float* ws_sp  = ws_u + BSZ * Hdim;                   // 8*L*B    = 65536
    float* ws_x   = ws_sp + 8 * LSEQ * BSZ;              // B*2H     = 131072
    float* ws_gx4 = ws_x + BSZ * 2 * Hdim;               // 4*B*3H   = 786432
    float* ws_gh4 = ws_gx4 + 4 * BSZ * 3 * Hdim;         // 4*B*3H   = 786432
    float* ws_oc  = ws_gh4 + 4 * BSZ * 3 * Hdim;         // B*3H     = 196608

    // 1. u partials: h0 @ W2^T, split-K x4 (32 blocks)
    gemm_bt_bf16<<<dim3(Hdim / 128, 4), 256, 0, stream>>>(
        hidden, Hdim, attnW + Hdim, 2 * Hdim, nullptr,
        ws_u4, Hdim, (size_t)BSZ * Hdim, 256);

    // 2. embedding gather (independent)
    embed_kernel<<<dim3(BSZ * Hdim / 256), 256, 0, stream>>>(ids, emb, ws_x, ws_oc);

    // 3. u = sum partials + attn_b
    ucomb<<<dim3(BSZ * Hdim / 256), 256, 0, stream>>>(ws_u4, attnb, ws_u);

    // 4. fused energy GEMM + tanh + v-reduction
    attn_scores_mfma<<<dim3(LSEQ, 8), 256, 0, stream>>>(enc, attnW, ws_u, vvec, ws_sp);

    // 5. softmax over L
    softmax_attn<<<dim3(BSZ), 128, 0, stream>>>(ws_sp, out_attn);

    // 6. weighted context
    weighted_kernel<<<dim3(BSZ * Hdim / 256), 256, 0, stream>>>(enc, out_attn, ws_x, ws_oc);

    // 7. GRU gate GEMMs, split-K x4 (96 blocks each)
    gemm_bt_bf16<<<dim3(3 * Hdim / 128, 4), 256, 0, stream>>>(
        ws_x, 2 * Hdim, w_ih, 2 * Hdim, nullptr,
        ws_gx4, 3 * Hdim, (size_t)BSZ * 3 * Hdim, 512);
    gemm_bt_bf16<<<dim3(3 * Hdim / 128, 4), 256, 0, stream>>>(
        hidden, Hdim, w_hh, Hdim, nullptr,
        ws_gh4, 3 * Hdim, (size_t)BSZ * 3 * Hdim, 256);

    // 8. GRU elementwise
    gru_kernel<<<dim3(BSZ * Hdim / 256), 256, 0, stream>>>(
        ws_gx4, ws_gh4, b_ih, b_hh, hidden, out_hnew, ws_oc);

    // 9. output projection [B, VOC]
    gemm_bt_bf16<<<dim3(VOC / 128, 1), 256, 0, stream>>>(
        ws_oc, 3 * Hdim, out_W, 3 * Hdim, out_b,
        out_logits, VOC, 0, 3 * Hdim);
}

// Round 3
// 196.659 us; speedup vs baseline: 3.9042x; 1.4548x over previous
//
#include <hip/hip_runtime.h>
#include <math.h>

#define Hdim 1024
#define VOC 32000
#define LSEQ 128
#define BSZ 64

typedef __attribute__((ext_vector_type(8))) short bf16x8;
typedef __attribute__((ext_vector_type(4))) float f32x4;

__device__ __forceinline__ float fast_tanhf(float x) {
    return 1.0f - 2.0f / (__expf(2.0f * x) + 1.0f);
}
__device__ __forceinline__ float sigmoidf(float x) {
    return 1.0f / (1.0f + __expf(-x));
}
__device__ __forceinline__ short f2bf(float f) {
    unsigned u = __float_as_uint(f);
    unsigned r = (u + 0x7fffu + ((u >> 16) & 1u)) >> 16;
    return (short)r;
}
__device__ __forceinline__ float bf2f(short s) {
    return __uint_as_float(((unsigned)(unsigned short)s) << 16);
}

// 16 consecutive f32 -> 16 bf16 at dst (2x 16B stores)
__device__ __forceinline__ void stage16(const float* __restrict__ src, short* dst) {
    f32x4 v0 = *(const f32x4*)(src);
    f32x4 v1 = *(const f32x4*)(src + 4);
    f32x4 v2 = *(const f32x4*)(src + 8);
    f32x4 v3 = *(const f32x4*)(src + 12);
    bf16x8 p0, p1;
    p0[0] = f2bf(v0[0]); p0[1] = f2bf(v0[1]); p0[2] = f2bf(v0[2]); p0[3] = f2bf(v0[3]);
    p0[4] = f2bf(v1[0]); p0[5] = f2bf(v1[1]); p0[6] = f2bf(v1[2]); p0[7] = f2bf(v1[3]);
    p1[0] = f2bf(v2[0]); p1[1] = f2bf(v2[1]); p1[2] = f2bf(v2[2]); p1[3] = f2bf(v2[3]);
    p1[4] = f2bf(v3[0]); p1[5] = f2bf(v3[1]); p1[6] = f2bf(v3[2]); p1[7] = f2bf(v3[3]);
    *(bf16x8*)(dst) = p0;
    *(bf16x8*)(dst + 8) = p1;
}

// ---------------------------------------------------------------------------
// One-pass f32 -> bf16 conversion of enc, attn_W, hidden (grid-stride).
// ---------------------------------------------------------------------------
__global__ __launch_bounds__(256) void convert_bf16(
    const float* __restrict__ enc, const float* __restrict__ attnW,
    const float* __restrict__ hidden,
    short* __restrict__ enc_bf, short* __restrict__ attnW_bf,
    short* __restrict__ hidden_bf)
{
    const int NG_ENC = (LSEQ * BSZ * Hdim) / 8;   // 1048576
    const int NG_AW  = (Hdim * 2 * Hdim) / 8;     // 262144
    const int NG_H   = (BSZ * Hdim) / 8;          // 8192
    const int total = NG_ENC + NG_AW + NG_H;
    for (int g = blockIdx.x * 256 + threadIdx.x; g < total; g += gridDim.x * 256) {
        const float* src; short* dst; int idx;
        if (g < NG_ENC)              { src = enc;    dst = enc_bf;    idx = g; }
        else if (g < NG_ENC + NG_AW) { src = attnW;  dst = attnW_bf;  idx = g - NG_ENC; }
        else                         { src = hidden; dst = hidden_bf; idx = g - NG_ENC - NG_AW; }
        f32x4 a = *(const f32x4*)(src + (size_t)idx * 8);
        f32x4 b = *(const f32x4*)(src + (size_t)idx * 8 + 4);
        bf16x8 p;
        p[0] = f2bf(a[0]); p[1] = f2bf(a[1]); p[2] = f2bf(a[2]); p[3] = f2bf(a[3]);
        p[4] = f2bf(b[0]); p[5] = f2bf(b[1]); p[6] = f2bf(b[2]); p[7] = f2bf(b[3]);
        *(bf16x8*)(dst + (size_t)idx * 8) = p;
    }
}

// ---------------------------------------------------------------------------
// bf16-MFMA TN GEMM partial: C_s = A[64,klen] @ B[n0:n0+128, klen]^T
// A bf16 pre-converted; B either bf16 (BF32=false) or f32 staged-in (true).
// 256 threads = 4 waves, BK=64, no bias (partials combined downstream).
// ---------------------------------------------------------------------------
template<bool BF32>
__global__ __launch_bounds__(256) void gemm256(
    const short* __restrict__ A, int lda,
    const void* __restrict__ Bv, int ldb,
    float* __restrict__ C, int ldc, size_t part_stride, int klen)
{
    __shared__ short As[64 * 72];
    __shared__ short Bs[128 * 72];

    const int t = threadIdx.x;
    const int lane = t & 63, wave = t >> 6;
    const int lr = lane & 15, kh = lane >> 4;
    const int n0 = blockIdx.x * 128;
    const int kstart = blockIdx.y * klen;
    float* Cp = C + (size_t)blockIdx.y * part_stride;

    const int ar = t >> 2, ac = (t & 3) * 16;   // A: 64 rows x 64 cols
    const int br = t >> 1, bc = (t & 1) * 32;   // B: 128 rows x 64 cols

    f32x4 acc[4][2] = {};

    for (int k0 = 0; k0 < klen; k0 += 64) {
        const int kg = kstart + k0;
        {
            const short* s = A + (size_t)ar * lda + kg + ac;
            *(bf16x8*)(As + ar * 72 + ac)     = *(const bf16x8*)(s);
            *(bf16x8*)(As + ar * 72 + ac + 8) = *(const bf16x8*)(s + 8);
        }
        if (!BF32) {
            const short* B = (const short*)Bv;
            const short* s = B + (size_t)(n0 + br) * ldb + kg + bc;
            short* d = Bs + br * 72 + bc;
            *(bf16x8*)(d)      = *(const bf16x8*)(s);
            *(bf16x8*)(d + 8)  = *(const bf16x8*)(s + 8);
            *(bf16x8*)(d + 16) = *(const bf16x8*)(s + 16);
            *(bf16x8*)(d + 24) = *(const bf16x8*)(s + 24);
        } else {
            const float* B = (const float*)Bv;
            const float* s = B + (size_t)(n0 + br) * ldb + kg + bc;
            stage16(s,      Bs + br * 72 + bc);
            stage16(s + 16, Bs + br * 72 + bc + 16);
        }
        __syncthreads();
#pragma unroll
        for (int kk = 0; kk < 64; kk += 32) {
            bf16x8 af[4], bfr[2];
#pragma unroll
            for (int mi = 0; mi < 4; ++mi)
                af[mi] = *(const bf16x8*)(As + (mi * 16 + lr) * 72 + kk + kh * 8);
#pragma unroll
            for (int ni = 0; ni < 2; ++ni)
                bfr[ni] = *(const bf16x8*)(Bs + (wave * 32 + ni * 16 + lr) * 72 + kk + kh * 8);
#pragma unroll
            for (int mi = 0; mi < 4; ++mi)
#pragma unroll
                for (int ni = 0; ni < 2; ++ni)
                    acc[mi][ni] = __builtin_amdgcn_mfma_f32_16x16x32_bf16(
                        af[mi], bfr[ni], acc[mi][ni], 0, 0, 0);
        }
        __syncthreads();
    }

#pragma unroll
    for (int mi = 0; mi < 4; ++mi)
#pragma unroll
        for (int ni = 0; ni < 2; ++ni) {
            const int col = n0 + wave * 32 + ni * 16 + lr;
#pragma unroll
            for (int r = 0; r < 4; ++r) {
                const int row = mi * 16 + kh * 4 + r;
                Cp[(size_t)row * ldc + col] = acc[mi][ni][r];
            }
        }
}

// ---------------------------------------------------------------------------
// Fused attention scores, all-bf16 staging.
// ---------------------------------------------------------------------------
__global__ __launch_bounds__(256) void attn_scores_mfma(
    const short* __restrict__ enc_bf,   // [8192, 1024]
    const short* __restrict__ W1_bf,    // attnW_bf, ld 2048, cols [0,1024)
    const float* __restrict__ u,        // [64, 1024]
    const float* __restrict__ vvec,     // [1024]
    float* __restrict__ scores_part)    // [8][8192]
{
    __shared__ short As[64 * 72];
    __shared__ short Bs[128 * 72];
    __shared__ float red[4][64];

    const int t = threadIdx.x;
    const int lane = t & 63, wave = t >> 6;
    const int lr = lane & 15, kh = lane >> 4;
    const int m0 = blockIdx.x * 64;
    const int n0 = blockIdx.y * 128;

    const int ar = t >> 2, ac = (t & 3) * 16;
    const int br = t >> 1, bc = (t & 1) * 32;

    f32x4 acc[4][2] = {};

    for (int kg = 0; kg < Hdim; kg += 64) {
        {
            const short* s = enc_bf + (size_t)(m0 + ar) * Hdim + kg + ac;
            *(bf16x8*)(As + ar * 72 + ac)     = *(const bf16x8*)(s);
            *(bf16x8*)(As + ar * 72 + ac + 8) = *(const bf16x8*)(s + 8);
        }
        {
            const short* s = W1_bf + (size_t)(n0 + br) * (2 * Hdim) + kg + bc;
            short* d = Bs + br * 72 + bc;
            *(bf16x8*)(d)      = *(const bf16x8*)(s);
            *(bf16x8*)(d + 8)  = *(const bf16x8*)(s + 8);
            *(bf16x8*)(d + 16) = *(const bf16x8*)(s + 16);
            *(bf16x8*)(d + 24) = *(const bf16x8*)(s + 24);
        }
        __syncthreads();
#pragma unroll
        for (int kk = 0; kk < 64; kk += 32) {
            bf16x8 af[4], bfr[2];
#pragma unroll
            for (int mi = 0; mi < 4; ++mi)
                af[mi] = *(const bf16x8*)(As + (mi * 16 + lr) * 72 + kk + kh * 8);
#pragma unroll
            for (int ni = 0; ni < 2; ++ni)
                bfr[ni] = *(const bf16x8*)(Bs + (wave * 32 + ni * 16 + lr) * 72 + kk + kh * 8);
#pragma unroll
            for (int mi = 0; mi < 4; ++mi)
#pragma unroll
                for (int ni = 0; ni < 2; ++ni)
                    acc[mi][ni] = __builtin_amdgcn_mfma_f32_16x16x32_bf16(
                        af[mi], bfr[ni], acc[mi][ni], 0, 0, 0);
        }
        __syncthreads();
    }

    float sv[16];
#pragma unroll
    for (int mi = 0; mi < 4; ++mi)
#pragma unroll
        for (int r = 0; r < 4; ++r) {
            const int row = mi * 16 + kh * 4 + r;   // local m == b
            float s = 0.0f;
#pragma unroll
            for (int ni = 0; ni < 2; ++ni) {
                const int h = n0 + wave * 32 + ni * 16 + lr;
                const float e = fast_tanhf(acc[mi][ni][r] + u[(size_t)row * Hdim + h]);
                s += e * vvec[h];
            }
            sv[mi * 4 + r] = s;
        }
#pragma unroll
    for (int i = 0; i < 16; ++i) {
#pragma unroll
        for (int d = 1; d < 16; d <<= 1)
            sv[i] += __shfl_xor(sv[i], d, 64);
    }
    if (lr == 0) {
#pragma unroll
        for (int mi = 0; mi < 4; ++mi)
#pragma unroll
            for (int r = 0; r < 4; ++r)
                red[wave][mi * 16 + kh * 4 + r] = sv[mi * 4 + r];
    }
    __syncthreads();
    if (t < 64)
        scores_part[(size_t)blockIdx.y * (LSEQ * BSZ) + m0 + t] =
            red[0][t] + red[1][t] + red[2][t] + red[3][t];
}

// ---------------------------------------------------------------------------
// Fused: u = sum(u4) + attn_b  AND  embedding gather (bf16 writes).
// ---------------------------------------------------------------------------
__global__ __launch_bounds__(256) void embed_ucomb(
    const float* __restrict__ u4, const float* __restrict__ attnb,
    const int* __restrict__ ids, const float* __restrict__ emb,
    float* __restrict__ u, short* __restrict__ x_bf, short* __restrict__ oc_bf)
{
    const int idx = blockIdx.x * 256 + threadIdx.x;   // 0 .. 131071
    if (idx < BSZ * Hdim) {
        u[idx] = u4[idx] + u4[65536 + idx] + u4[2 * 65536 + idx] + u4[3 * 65536 + idx]
               + attnb[idx & 1023];
    } else {
        const int j = idx - BSZ * Hdim;
        const int b = j >> 10, h = j & 1023;
        const short e = f2bf(emb[(size_t)ids[b] * Hdim + h]);
        x_bf[(size_t)b * 2048 + h] = e;
        oc_bf[(size_t)b * 3072 + 2048 + h] = e;
    }
}

// ---------------------------------------------------------------------------
// Fused softmax (over L) + weighted context. One block per b.
// ---------------------------------------------------------------------------
__global__ __launch_bounds__(256) void softmax_weighted(
    const float* __restrict__ sp,       // [8][8192]
    const short* __restrict__ enc_bf,   // [8192, 1024]
    float* __restrict__ attn_out,       // [B, L]
    short* __restrict__ x_bf,           // [64, 2048]
    short* __restrict__ oc_bf)          // [64, 3072]
{
    const int b = blockIdx.x, t = threadIdx.x;
    __shared__ float aw[LSEQ];
    __shared__ float red[128];

    float s = 0.0f;
    if (t < 128) {
#pragma unroll
        for (int g = 0; g < 8; ++g) s += sp[g * (LSEQ * BSZ) + t * 64 + b];
        red[t] = s;
    }
    __syncthreads();
    for (int off = 64; off > 0; off >>= 1) {
        if (t < off) red[t] = fmaxf(red[t], red[t + off]);
        __syncthreads();
    }
    const float mx = red[0];
    __syncthreads();
    float e = 0.0f;
    if (t < 128) { e = __expf(s - mx); red[t] = e; }
    __syncthreads();
    for (int off = 64; off > 0; off >>= 1) {
        if (t < off) red[t] += red[t + off];
        __syncthreads();
    }
    const float inv = 1.0f / red[0];
    if (t < 128) {
        const float p = e * inv;
        aw[t] = p;
        attn_out[(size_t)b * LSEQ + t] = p;
    }
    __syncthreads();

    // weighted: each thread 2 consecutive h per chunk, 2 chunks
#pragma unroll
    for (int c = 0; c < 2; ++c) {
        const int h = c * 512 + t * 2;
        float a0 = 0.0f, a1 = 0.0f;
        for (int l = 0; l < LSEQ; ++l) {
            const unsigned w = *(const unsigned*)(enc_bf + ((size_t)l * BSZ + b) * Hdim + h);
            const float p = aw[l];
            a0 = fmaf(p, __uint_as_float(w << 16), a0);
            a1 = fmaf(p, __uint_as_float(w & 0xffff0000u), a1);
        }
        const unsigned packed = (unsigned)(unsigned short)f2bf(a0)
                              | ((unsigned)(unsigned short)f2bf(a1) << 16);
        *(unsigned*)(x_bf + (size_t)b * 2048 + 1024 + h) = packed;
        *(unsigned*)(oc_bf + (size_t)b * 3072 + 1024 + h) = packed;
    }
}

// ---------------------------------------------------------------------------
// GRU elementwise; sums 4 split-K partials + biases; bf16 out_cat write.
// ---------------------------------------------------------------------------
__global__ __launch_bounds__(256) void gru_kernel(
    const float* __restrict__ gx4, const float* __restrict__ gh4,
    const float* __restrict__ b_ih, const float* __restrict__ b_hh,
    const float* __restrict__ h0,
    float* __restrict__ hnew_out, short* __restrict__ oc_bf)
{
    const int idx = blockIdx.x * 256 + threadIdx.x;
    const int b = idx >> 10, h = idx & 1023;
    const size_t g3 = (size_t)b * (3 * Hdim);
    const size_t P = (size_t)BSZ * 3 * Hdim;
    float xr = b_ih[h], xz = b_ih[Hdim + h], xn = b_ih[2 * Hdim + h];
    float hr = b_hh[h], hz = b_hh[Hdim + h], hn = b_hh[2 * Hdim + h];
#pragma unroll
    for (int s = 0; s < 4; ++s) {
        xr += gx4[s * P + g3 + h];
        xz += gx4[s * P + g3 + Hdim + h];
        xn += gx4[s * P + g3 + 2 * Hdim + h];
        hr += gh4[s * P + g3 + h];
        hz += gh4[s * P + g3 + Hdim + h];
        hn += gh4[s * P + g3 + 2 * Hdim + h];
    }
    const float r = sigmoidf(xr + hr);
    const float z = sigmoidf(xz + hz);
    const float n = fast_tanhf(xn + r * hn);
    const float hv = (1.0f - z) * n + z * h0[(size_t)b * Hdim + h];
    hnew_out[(size_t)b * Hdim + h] = hv;
    oc_bf[g3 + h] = f2bf(hv);
}

// ---------------------------------------------------------------------------
// Output projection partial: 512 threads = 8 waves, BM=64, BN=128, BK=64.
// A bf16 (out_cat), B f32 (out_W) staged with in-register conversion.
// ---------------------------------------------------------------------------
__global__ __launch_bounds__(512) void outproj512(
    const short* __restrict__ A,    // [64, 3072] bf16
    const float* __restrict__ B,    // [32000, 3072] f32
    float* __restrict__ Cpart,      // [2][64, 32000]
    int klen)
{
    __shared__ short As[64 * 72];
    __shared__ short Bs[128 * 72];

    const int t = threadIdx.x;
    const int lane = t & 63, wave = t >> 6;   // 8 waves
    const int lr = lane & 15, kh = lane >> 4;
    const int n0 = blockIdx.x * 128;
    const int kstart = blockIdx.y * klen;
    float* Cp = Cpart + (size_t)blockIdx.y * (64 * VOC);

    const int ar = t >> 3, ac = (t & 7) * 8;    // A: 64 x 64, 16B per thread
    const int br = t >> 2, bc = (t & 3) * 16;   // B: 128 x 64, 16 f32 per thread

    f32x4 acc[4] = {};

    for (int k0 = 0; k0 < klen; k0 += 64) {
        const int kg = kstart + k0;
        *(bf16x8*)(As + ar * 72 + ac) =
            *(const bf16x8*)(A + (size_t)ar * 3072 + kg + ac);
        stage16(B + (size_t)(n0 + br) * 3072 + kg + bc, Bs + br * 72 + bc);
        __syncthreads();
#pragma unroll
        for (int kk = 0; kk < 64; kk += 32) {
            bf16x8 af[4], bfr;
#pragma unroll
            for (int mi = 0; mi < 4; ++mi)
                af[mi] = *(const bf16x8*)(As + (mi * 16 + lr) * 72 + kk + kh * 8);
            bfr = *(const bf16x8*)(Bs + (wave * 16 + lr) * 72 + kk + kh * 8);
#pragma unroll
            for (int mi = 0; mi < 4; ++mi)
                acc[mi] = __builtin_amdgcn_mfma_f32_16x16x32_bf16(af[mi], bfr, acc[mi], 0, 0, 0);
        }
        __syncthreads();
    }

    const int col = n0 + wave * 16 + lr;
#pragma unroll
    for (int mi = 0; mi < 4; ++mi)
#pragma unroll
        for (int r = 0; r < 4; ++r) {
            const int row = mi * 16 + kh * 4 + r;
            Cp[(size_t)row * VOC + col] = acc[mi][r];
        }
}

// ---------------------------------------------------------------------------
// Combine out-proj split-K partials + bias.
// ---------------------------------------------------------------------------
__global__ __launch_bounds__(256) void oproj_comb(
    const float* __restrict__ part, const float* __restrict__ out_b,
    float* __restrict__ logits)
{
    const size_t i4 = ((size_t)blockIdx.x * 256 + threadIdx.x) * 4;  // < 64*32000
    f32x4 a = *(const f32x4*)(part + i4);
    f32x4 b = *(const f32x4*)(part + (size_t)64 * VOC + i4);
    const int col = (int)(i4 % VOC);
    f32x4 bb = *(const f32x4*)(out_b + col);
    f32x4 o = a + b + bb;
    *(f32x4*)(logits + i4) = o;
}

// ---------------------------------------------------------------------------
extern "C" void kernel_launch(void* const* d_in, const int* in_sizes, int n_in,
                              void* d_out, int out_size, void* d_ws, size_t ws_size,
                              hipStream_t stream)
{
    const int*   ids    = (const int*)d_in[0];
    const float* hidden = (const float*)d_in[1];
    const float* enc    = (const float*)d_in[2];
    const float* emb    = (const float*)d_in[3];
    const float* attnW  = (const float*)d_in[4];
    const float* attnb  = (const float*)d_in[5];
    const float* vvec   = (const float*)d_in[6];
    const float* w_ih   = (const float*)d_in[7];
    const float* w_hh   = (const float*)d_in[8];
    const float* b_ih   = (const float*)d_in[9];
    const float* b_hh   = (const float*)d_in[10];
    const float* out_W  = (const float*)d_in[11];
    const float* out_b  = (const float*)d_in[12];

    float* out        = (float*)d_out;
    float* out_logits = out;
    float* out_hnew   = out + (size_t)BSZ * VOC;
    float* out_attn   = out_hnew + (size_t)BSZ * Hdim;

    float* ws = (float*)d_ws;
    short* enc_bf    = (short*)ws;                        // 8388608 shorts
    short* attnW_bf  = (short*)(ws + 4194304);            // 2097152 shorts
    short* hidden_bf = (short*)(ws + 4194304 + 1048576);  // 65536 shorts
    float* ws_u4  = ws + 4194304 + 1048576 + 32768;       // 262144 f
    float* ws_u   = ws_u4 + 262144;                       // 65536 f
    float* ws_sp  = ws_u + 65536;                         // 65536 f
    short* x_bf   = (short*)(ws_sp + 65536);              // 131072 shorts
    short* oc_bf  = (short*)(ws_sp + 65536 + 65536);      // 196608 shorts
    float* ws_gx4 = ws_sp + 65536 + 65536 + 98304;        // 786432 f
    float* ws_gh4 = ws_gx4 + 786432;                      // 786432 f
    float* ws_op  = ws_gh4 + 786432;                      // 2*2048000 f

    // 1. f32 -> bf16 one-pass conversion
    convert_bf16<<<dim3(1024), 256, 0, stream>>>(
        enc, attnW, hidden, enc_bf, attnW_bf, hidden_bf);

    // 2. u partials: hidden_bf @ W2_bf^T (split-K x4)
    gemm256<false><<<dim3(Hdim / 128, 4), 256, 0, stream>>>(
        hidden_bf, Hdim, attnW_bf + Hdim, 2 * Hdim,
        ws_u4, Hdim, (size_t)BSZ * Hdim, 256);

    // 3. u combine + embedding gather
    embed_ucomb<<<dim3(2 * BSZ * Hdim / 256), 256, 0, stream>>>(
        ws_u4, attnb, ids, emb, ws_u, x_bf, oc_bf);

    // 4. fused energy GEMM + tanh + v-reduction
    attn_scores_mfma<<<dim3(LSEQ, 8), 256, 0, stream>>>(
        enc_bf, attnW_bf, ws_u, vvec, ws_sp);

    // 5. softmax + weighted context
    softmax_weighted<<<dim3(BSZ), 256, 0, stream>>>(
        ws_sp, enc_bf, out_attn, x_bf, oc_bf);

    // 6. GRU gate GEMMs (split-K x4)
    gemm256<true><<<dim3(3 * Hdim / 128, 4), 256, 0, stream>>>(
        x_bf, 2 * Hdim, w_ih, 2 * Hdim,
        ws_gx4, 3 * Hdim, (size_t)BSZ * 3 * Hdim, 512);
    gemm256<true><<<dim3(3 * Hdim / 128, 4), 256, 0, stream>>>(
        hidden_bf, Hdim, w_hh, Hdim,
        ws_gh4, 3 * Hdim, (size_t)BSZ * 3 * Hdim, 256);

    // 7. GRU elementwise
    gru_kernel<<<dim3(BSZ * Hdim / 256), 256, 0, stream>>>(
        ws_gx4, ws_gh4, b_ih, b_hh, hidden, out_hnew, oc_bf);

    // 8. output projection (split-K x2, 500 blocks) + combine
    outproj512<<<dim3(VOC / 128, 2), 512, 0, stream>>>(
        oc_bf, out_W, ws_op, 1536);
    oproj_comb<<<dim3(BSZ * VOC / 4 / 256), 256, 0, stream>>>(
        ws_op, out_b, out_logits);
}

// Round 4
// 191.523 us; speedup vs baseline: 4.0089x; 1.0268x over previous
//
#include <hip/hip_runtime.h>
#include <math.h>

#define Hdim 1024
#define VOC 32000
#define LSEQ 128
#define BSZ 64

typedef __attribute__((ext_vector_type(8))) short bf16x8;
typedef __attribute__((ext_vector_type(4))) float f32x4;

__device__ __forceinline__ float fast_tanhf(float x) {
    return 1.0f - 2.0f / (__expf(2.0f * x) + 1.0f);
}
__device__ __forceinline__ float sigmoidf(float x) {
    return 1.0f / (1.0f + __expf(-x));
}
__device__ __forceinline__ short f2bf(float f) {
    unsigned u = __float_as_uint(f);
    unsigned r = (u + 0x7fffu + ((u >> 16) & 1u)) >> 16;
    return (short)r;
}

// 16 consecutive f32 -> 16 bf16 at dst (2x 16B stores)
__device__ __forceinline__ void stage16(const float* __restrict__ src, short* dst) {
    f32x4 v0 = *(const f32x4*)(src);
    f32x4 v1 = *(const f32x4*)(src + 4);
    f32x4 v2 = *(const f32x4*)(src + 8);
    f32x4 v3 = *(const f32x4*)(src + 12);
    bf16x8 p0, p1;
    p0[0] = f2bf(v0[0]); p0[1] = f2bf(v0[1]); p0[2] = f2bf(v0[2]); p0[3] = f2bf(v0[3]);
    p0[4] = f2bf(v1[0]); p0[5] = f2bf(v1[1]); p0[6] = f2bf(v1[2]); p0[7] = f2bf(v1[3]);
    p1[0] = f2bf(v2[0]); p1[1] = f2bf(v2[1]); p1[2] = f2bf(v2[2]); p1[3] = f2bf(v2[3]);
    p1[4] = f2bf(v3[0]); p1[5] = f2bf(v3[1]); p1[6] = f2bf(v3[2]); p1[7] = f2bf(v3[3]);
    *(bf16x8*)(dst) = p0;
    *(bf16x8*)(dst + 8) = p1;
}

// ---------------------------------------------------------------------------
// One-pass f32 -> bf16 conversion of enc, attn_W, hidden (grid-stride).
// ---------------------------------------------------------------------------
__global__ __launch_bounds__(256) void convert_bf16(
    const float* __restrict__ enc, const float* __restrict__ attnW,
    const float* __restrict__ hidden,
    short* __restrict__ enc_bf, short* __restrict__ attnW_bf,
    short* __restrict__ hidden_bf)
{
    const int NG_ENC = (LSEQ * BSZ * Hdim) / 8;   // 1048576
    const int NG_AW  = (Hdim * 2 * Hdim) / 8;     // 262144
    const int NG_H   = (BSZ * Hdim) / 8;          // 8192
    const int total = NG_ENC + NG_AW + NG_H;
    for (int g = blockIdx.x * 256 + threadIdx.x; g < total; g += gridDim.x * 256) {
        const float* src; short* dst; int idx;
        if (g < NG_ENC)              { src = enc;    dst = enc_bf;    idx = g; }
        else if (g < NG_ENC + NG_AW) { src = attnW;  dst = attnW_bf;  idx = g - NG_ENC; }
        else                         { src = hidden; dst = hidden_bf; idx = g - NG_ENC - NG_AW; }
        f32x4 a = *(const f32x4*)(src + (size_t)idx * 8);
        f32x4 b = *(const f32x4*)(src + (size_t)idx * 8 + 4);
        bf16x8 p;
        p[0] = f2bf(a[0]); p[1] = f2bf(a[1]); p[2] = f2bf(a[2]); p[3] = f2bf(a[3]);
        p[4] = f2bf(b[0]); p[5] = f2bf(b[1]); p[6] = f2bf(b[2]); p[7] = f2bf(b[3]);
        *(bf16x8*)(dst + (size_t)idx * 8) = p;
    }
}

// ---------------------------------------------------------------------------
// bf16-MFMA TN GEMM partial: C_s = A[64,klen] @ B[n0:n0+128, klen]^T
// ---------------------------------------------------------------------------
template<bool BF32>
__global__ __launch_bounds__(256) void gemm256(
    const short* __restrict__ A, int lda,
    const void* __restrict__ Bv, int ldb,
    float* __restrict__ C, int ldc, size_t part_stride, int klen)
{
    __shared__ short As[64 * 72];
    __shared__ short Bs[128 * 72];

    const int t = threadIdx.x;
    const int lane = t & 63, wave = t >> 6;
    const int lr = lane & 15, kh = lane >> 4;
    const int n0 = blockIdx.x * 128;
    const int kstart = blockIdx.y * klen;
    float* Cp = C + (size_t)blockIdx.y * part_stride;

    const int ar = t >> 2, ac = (t & 3) * 16;
    const int br = t >> 1, bc = (t & 1) * 32;

    f32x4 acc[4][2] = {};

    for (int k0 = 0; k0 < klen; k0 += 64) {
        const int kg = kstart + k0;
        {
            const short* s = A + (size_t)ar * lda + kg + ac;
            *(bf16x8*)(As + ar * 72 + ac)     = *(const bf16x8*)(s);
            *(bf16x8*)(As + ar * 72 + ac + 8) = *(const bf16x8*)(s + 8);
        }
        if (!BF32) {
            const short* B = (const short*)Bv;
            const short* s = B + (size_t)(n0 + br) * ldb + kg + bc;
            short* d = Bs + br * 72 + bc;
            *(bf16x8*)(d)      = *(const bf16x8*)(s);
            *(bf16x8*)(d + 8)  = *(const bf16x8*)(s + 8);
            *(bf16x8*)(d + 16) = *(const bf16x8*)(s + 16);
            *(bf16x8*)(d + 24) = *(const bf16x8*)(s + 24);
        } else {
            const float* B = (const float*)Bv;
            const float* s = B + (size_t)(n0 + br) * ldb + kg + bc;
            stage16(s,      Bs + br * 72 + bc);
            stage16(s + 16, Bs + br * 72 + bc + 16);
        }
        __syncthreads();
#pragma unroll
        for (int kk = 0; kk < 64; kk += 32) {
            bf16x8 af[4], bfr[2];
#pragma unroll
            for (int mi = 0; mi < 4; ++mi)
                af[mi] = *(const bf16x8*)(As + (mi * 16 + lr) * 72 + kk + kh * 8);
#pragma unroll
            for (int ni = 0; ni < 2; ++ni)
                bfr[ni] = *(const bf16x8*)(Bs + (wave * 32 + ni * 16 + lr) * 72 + kk + kh * 8);
#pragma unroll
            for (int mi = 0; mi < 4; ++mi)
#pragma unroll
                for (int ni = 0; ni < 2; ++ni)
                    acc[mi][ni] = __builtin_amdgcn_mfma_f32_16x16x32_bf16(
                        af[mi], bfr[ni], acc[mi][ni], 0, 0, 0);
        }
        __syncthreads();
    }

#pragma unroll
    for (int mi = 0; mi < 4; ++mi)
#pragma unroll
        for (int ni = 0; ni < 2; ++ni) {
            const int col = n0 + wave * 32 + ni * 16 + lr;
#pragma unroll
            for (int r = 0; r < 4; ++r) {
                const int row = mi * 16 + kh * 4 + r;
                Cp[(size_t)row * ldc + col] = acc[mi][ni][r];
            }
        }
}

// ---------------------------------------------------------------------------
// Fused attention scores, 128x128 tile, 512 threads = 8 waves (2x4).
// energy[m,h] = enc[m,:] . W1[h,:]; partial[g][m] = sum_h v[h]*tanh(e + u[b,h])
// grid = (64 m-tiles, 8 col-groups).
// ---------------------------------------------------------------------------
__global__ __launch_bounds__(512) void attn_scores_mfma(
    const short* __restrict__ enc_bf,   // [8192, 1024]
    const short* __restrict__ W1_bf,    // ld 2048, cols [0,1024)
    const float* __restrict__ u,        // [64, 1024]
    const float* __restrict__ vvec,     // [1024]
    float* __restrict__ scores_part)    // [8][8192]
{
    __shared__ short As[128 * 72];
    __shared__ short Bs[128 * 72];
    __shared__ float red[8][64];

    const int t = threadIdx.x;
    const int lane = t & 63, wave = t >> 6;     // 8 waves
    const int wr = wave >> 2, wc = wave & 3;    // 2 x 4 wave grid
    const int lr = lane & 15, kh = lane >> 4;
    const int m0 = blockIdx.x * 128;
    const int n0 = blockIdx.y * 128;

    const int srow = t >> 2, scol = (t & 3) * 16;  // staging: 128 rows x 64 cols

    f32x4 acc[4][2] = {};

    for (int kg = 0; kg < Hdim; kg += 64) {
        {
            const short* s = enc_bf + (size_t)(m0 + srow) * Hdim + kg + scol;
            *(bf16x8*)(As + srow * 72 + scol)     = *(const bf16x8*)(s);
            *(bf16x8*)(As + srow * 72 + scol + 8) = *(const bf16x8*)(s + 8);
        }
        {
            const short* s = W1_bf + (size_t)(n0 + srow) * (2 * Hdim) + kg + scol;
            *(bf16x8*)(Bs + srow * 72 + scol)     = *(const bf16x8*)(s);
            *(bf16x8*)(Bs + srow * 72 + scol + 8) = *(const bf16x8*)(s + 8);
        }
        __syncthreads();
#pragma unroll
        for (int kk = 0; kk < 64; kk += 32) {
            bf16x8 af[4], bfr[2];
#pragma unroll
            for (int mi = 0; mi < 4; ++mi)
                af[mi] = *(const bf16x8*)(As + (wr * 64 + mi * 16 + lr) * 72 + kk + kh * 8);
#pragma unroll
            for (int ni = 0; ni < 2; ++ni)
                bfr[ni] = *(const bf16x8*)(Bs + (wc * 32 + ni * 16 + lr) * 72 + kk + kh * 8);
#pragma unroll
            for (int mi = 0; mi < 4; ++mi)
#pragma unroll
                for (int ni = 0; ni < 2; ++ni)
                    acc[mi][ni] = __builtin_amdgcn_mfma_f32_16x16x32_bf16(
                        af[mi], bfr[ni], acc[mi][ni], 0, 0, 0);
        }
        __syncthreads();
    }

    // epilogue: tanh + v-weight, reduce over this block's 128 h-cols
    float sv[16];
#pragma unroll
    for (int mi = 0; mi < 4; ++mi)
#pragma unroll
        for (int r = 0; r < 4; ++r) {
            const int lrow = mi * 16 + kh * 4 + r;          // 0..63 within wr half
            const int b = (wr * 64 + lrow) & 63;            // m0 % 64 == 0
            float s = 0.0f;
#pragma unroll
            for (int ni = 0; ni < 2; ++ni) {
                const int h = n0 + wc * 32 + ni * 16 + lr;
                const float e = fast_tanhf(acc[mi][ni][r] + u[(size_t)b * Hdim + h]);
                s += e * vvec[h];
            }
            sv[mi * 4 + r] = s;
        }
#pragma unroll
    for (int i = 0; i < 16; ++i) {
#pragma unroll
        for (int d = 1; d < 16; d <<= 1)
            sv[i] += __shfl_xor(sv[i], d, 64);
    }
    if (lr == 0) {
#pragma unroll
        for (int mi = 0; mi < 4; ++mi)
#pragma unroll
            for (int r = 0; r < 4; ++r)
                red[wave][mi * 16 + kh * 4 + r] = sv[mi * 4 + r];
    }
    __syncthreads();
    if (t < 128) {
        const int wrr = t >> 6, lrow = t & 63;
        scores_part[(size_t)blockIdx.y * (LSEQ * BSZ) + m0 + t] =
            red[wrr * 4 + 0][lrow] + red[wrr * 4 + 1][lrow] +
            red[wrr * 4 + 2][lrow] + red[wrr * 4 + 3][lrow];
    }
}

// ---------------------------------------------------------------------------
// Fused: u = sum(u4) + attn_b  AND  embedding gather (bf16 writes).
// ---------------------------------------------------------------------------
__global__ __launch_bounds__(256) void embed_ucomb(
    const float* __restrict__ u4, const float* __restrict__ attnb,
    const int* __restrict__ ids, const float* __restrict__ emb,
    float* __restrict__ u, short* __restrict__ x_bf, short* __restrict__ oc_bf)
{
    const int idx = blockIdx.x * 256 + threadIdx.x;   // 0 .. 131071
    if (idx < BSZ * Hdim) {
        u[idx] = u4[idx] + u4[65536 + idx] + u4[2 * 65536 + idx] + u4[3 * 65536 + idx]
               + attnb[idx & 1023];
    } else {
        const int j = idx - BSZ * Hdim;
        const int b = j >> 10, h = j & 1023;
        const short e = f2bf(emb[(size_t)ids[b] * Hdim + h]);
        x_bf[(size_t)b * 2048 + h] = e;
        oc_bf[(size_t)b * 3072 + 2048 + h] = e;
    }
}

// ---------------------------------------------------------------------------
// Fused softmax (over L) + weighted context. One block per b.
// ---------------------------------------------------------------------------
__global__ __launch_bounds__(256) void softmax_weighted(
    const float* __restrict__ sp,       // [8][8192]
    const short* __restrict__ enc_bf,   // [8192, 1024]
    float* __restrict__ attn_out,       // [B, L]
    short* __restrict__ x_bf,           // [64, 2048]
    short* __restrict__ oc_bf)          // [64, 3072]
{
    const int b = blockIdx.x, t = threadIdx.x;
    __shared__ float aw[LSEQ];
    __shared__ float red[128];

    float s = 0.0f;
    if (t < 128) {
#pragma unroll
        for (int g = 0; g < 8; ++g) s += sp[g * (LSEQ * BSZ) + t * 64 + b];
        red[t] = s;
    }
    __syncthreads();
    for (int off = 64; off > 0; off >>= 1) {
        if (t < off) red[t] = fmaxf(red[t], red[t + off]);
        __syncthreads();
    }
    const float mx = red[0];
    __syncthreads();
    float e = 0.0f;
    if (t < 128) { e = __expf(s - mx); red[t] = e; }
    __syncthreads();
    for (int off = 64; off > 0; off >>= 1) {
        if (t < off) red[t] += red[t + off];
        __syncthreads();
    }
    const float inv = 1.0f / red[0];
    if (t < 128) {
        const float p = e * inv;
        aw[t] = p;
        attn_out[(size_t)b * LSEQ + t] = p;
    }
    __syncthreads();

#pragma unroll
    for (int c = 0; c < 2; ++c) {
        const int h = c * 512 + t * 2;
        float a0 = 0.0f, a1 = 0.0f;
        for (int l = 0; l < LSEQ; ++l) {
            const unsigned w = *(const unsigned*)(enc_bf + ((size_t)l * BSZ + b) * Hdim + h);
            const float p = aw[l];
            a0 = fmaf(p, __uint_as_float(w << 16), a0);
            a1 = fmaf(p, __uint_as_float(w & 0xffff0000u), a1);
        }
        const unsigned packed = (unsigned)(unsigned short)f2bf(a0)
                              | ((unsigned)(unsigned short)f2bf(a1) << 16);
        *(unsigned*)(x_bf + (size_t)b * 2048 + 1024 + h) = packed;
        *(unsigned*)(oc_bf + (size_t)b * 3072 + 1024 + h) = packed;
    }
}

// ---------------------------------------------------------------------------
// GRU elementwise; sums 4 split-K partials + biases; bf16 out_cat write.
// ---------------------------------------------------------------------------
__global__ __launch_bounds__(256) void gru_kernel(
    const float* __restrict__ gx4, const float* __restrict__ gh4,
    const float* __restrict__ b_ih, const float* __restrict__ b_hh,
    const float* __restrict__ h0,
    float* __restrict__ hnew_out, short* __restrict__ oc_bf)
{
    const int idx = blockIdx.x * 256 + threadIdx.x;
    const int b = idx >> 10, h = idx & 1023;
    const size_t g3 = (size_t)b * (3 * Hdim);
    const size_t P = (size_t)BSZ * 3 * Hdim;
    float xr = b_ih[h], xz = b_ih[Hdim + h], xn = b_ih[2 * Hdim + h];
    float hr = b_hh[h], hz = b_hh[Hdim + h], hn = b_hh[2 * Hdim + h];
#pragma unroll
    for (int s = 0; s < 4; ++s) {
        xr += gx4[s * P + g3 + h];
        xz += gx4[s * P + g3 + Hdim + h];
        xn += gx4[s * P + g3 + 2 * Hdim + h];
        hr += gh4[s * P + g3 + h];
        hz += gh4[s * P + g3 + Hdim + h];
        hn += gh4[s * P + g3 + 2 * Hdim + h];
    }
    const float r = sigmoidf(xr + hr);
    const float z = sigmoidf(xz + hz);
    const float n = fast_tanhf(xn + r * hn);
    const float hv = (1.0f - z) * n + z * h0[(size_t)b * Hdim + h];
    hnew_out[(size_t)b * Hdim + h] = hv;
    oc_bf[g3 + h] = f2bf(hv);
}

// ---------------------------------------------------------------------------
// Output projection partial: 512 threads = 8 waves, BM=64, BN=128, BK=64.
// ---------------------------------------------------------------------------
__global__ __launch_bounds__(512) void outproj512(
    const short* __restrict__ A,    // [64, 3072] bf16
    const float* __restrict__ B,    // [32000, 3072] f32
    float* __restrict__ Cpart,      // [2][64, 32000]
    int klen)
{
    __shared__ short As[64 * 72];
    __shared__ short Bs[128 * 72];

    const int t = threadIdx.x;
    const int lane = t & 63, wave = t >> 6;
    const int lr = lane & 15, kh = lane >> 4;
    const int n0 = blockIdx.x * 128;
    const int kstart = blockIdx.y * klen;
    float* Cp = Cpart + (size_t)blockIdx.y * (64 * VOC);

    const int ar = t >> 3, ac = (t & 7) * 8;
    const int br = t >> 2, bc = (t & 3) * 16;

    f32x4 acc[4] = {};

    for (int k0 = 0; k0 < klen; k0 += 64) {
        const int kg = kstart + k0;
        *(bf16x8*)(As + ar * 72 + ac) =
            *(const bf16x8*)(A + (size_t)ar * 3072 + kg + ac);
        stage16(B + (size_t)(n0 + br) * 3072 + kg + bc, Bs + br * 72 + bc);
        __syncthreads();
#pragma unroll
        for (int kk = 0; kk < 64; kk += 32) {
            bf16x8 af[4], bfr;
#pragma unroll
            for (int mi = 0; mi < 4; ++mi)
                af[mi] = *(const bf16x8*)(As + (mi * 16 + lr) * 72 + kk + kh * 8);
            bfr = *(const bf16x8*)(Bs + (wave * 16 + lr) * 72 + kk + kh * 8);
#pragma unroll
            for (int mi = 0; mi < 4; ++mi)
                acc[mi] = __builtin_amdgcn_mfma_f32_16x16x32_bf16(af[mi], bfr, acc[mi], 0, 0, 0);
        }
        __syncthreads();
    }

    const int col = n0 + wave * 16 + lr;
#pragma unroll
    for (int mi = 0; mi < 4; ++mi)
#pragma unroll
        for (int r = 0; r < 4; ++r) {
            const int row = mi * 16 + kh * 4 + r;
            Cp[(size_t)row * VOC + col] = acc[mi][r];
        }
}

// ---------------------------------------------------------------------------
__global__ __launch_bounds__(256) void oproj_comb(
    const float* __restrict__ part, const float* __restrict__ out_b,
    float* __restrict__ logits)
{
    const size_t i4 = ((size_t)blockIdx.x * 256 + threadIdx.x) * 4;
    f32x4 a = *(const f32x4*)(part + i4);
    f32x4 b = *(const f32x4*)(part + (size_t)64 * VOC + i4);
    const int col = (int)(i4 % VOC);
    f32x4 bb = *(const f32x4*)(out_b + col);
    f32x4 o = a + b + bb;
    *(f32x4*)(logits + i4) = o;
}

// ---------------------------------------------------------------------------
extern "C" void kernel_launch(void* const* d_in, const int* in_sizes, int n_in,
                              void* d_out, int out_size, void* d_ws, size_t ws_size,
                              hipStream_t stream)
{
    const int*   ids    = (const int*)d_in[0];
    const float* hidden = (const float*)d_in[1];
    const float* enc    = (const float*)d_in[2];
    const float* emb    = (const float*)d_in[3];
    const float* attnW  = (const float*)d_in[4];
    const float* attnb  = (const float*)d_in[5];
    const float* vvec   = (const float*)d_in[6];
    const float* w_ih   = (const float*)d_in[7];
    const float* w_hh   = (const float*)d_in[8];
    const float* b_ih   = (const float*)d_in[9];
    const float* b_hh   = (const float*)d_in[10];
    const float* out_W  = (const float*)d_in[11];
    const float* out_b  = (const float*)d_in[12];

    float* out        = (float*)d_out;
    float* out_logits = out;
    float* out_hnew   = out + (size_t)BSZ * VOC;
    float* out_attn   = out_hnew + (size_t)BSZ * Hdim;

    float* ws = (float*)d_ws;
    short* enc_bf    = (short*)ws;                        // 8388608 shorts
    short* attnW_bf  = (short*)(ws + 4194304);            // 2097152 shorts
    short* hidden_bf = (short*)(ws + 4194304 + 1048576);  // 65536 shorts
    float* ws_u4  = ws + 4194304 + 1048576 + 32768;       // 262144 f
    float* ws_u   = ws_u4 + 262144;                       // 65536 f
    float* ws_sp  = ws_u + 65536;                         // 65536 f
    short* x_bf   = (short*)(ws_sp + 65536);              // 131072 shorts
    short* oc_bf  = (short*)(ws_sp + 65536 + 65536);      // 196608 shorts
    float* ws_gx4 = ws_sp + 65536 + 65536 + 98304;        // 786432 f
    float* ws_gh4 = ws_gx4 + 786432;                      // 786432 f
    float* ws_op  = ws_gh4 + 786432;                      // 2*2048000 f

    // 1. f32 -> bf16 one-pass conversion
    convert_bf16<<<dim3(1024), 256, 0, stream>>>(
        enc, attnW, hidden, enc_bf, attnW_bf, hidden_bf);

    // 2. u partials: hidden_bf @ W2_bf^T (split-K x4)
    gemm256<false><<<dim3(Hdim / 128, 4), 256, 0, stream>>>(
        hidden_bf, Hdim, attnW_bf + Hdim, 2 * Hdim,
        ws_u4, Hdim, (size_t)BSZ * Hdim, 256);

    // 3. u combine + embedding gather
    embed_ucomb<<<dim3(2 * BSZ * Hdim / 256), 256, 0, stream>>>(
        ws_u4, attnb, ids, emb, ws_u, x_bf, oc_bf);

    // 4. fused energy GEMM + tanh + v-reduction (128x128 tile, 8 waves)
    attn_scores_mfma<<<dim3(LSEQ / 2, 8), 512, 0, stream>>>(
        enc_bf, attnW_bf, ws_u, vvec, ws_sp);

    // 5. softmax + weighted context
    softmax_weighted<<<dim3(BSZ), 256, 0, stream>>>(
        ws_sp, enc_bf, out_attn, x_bf, oc_bf);

    // 6. GRU gate GEMMs (split-K x4)
    gemm256<true><<<dim3(3 * Hdim / 128, 4), 256, 0, stream>>>(
        x_bf, 2 * Hdim, w_ih, 2 * Hdim,
        ws_gx4, 3 * Hdim, (size_t)BSZ * 3 * Hdim, 512);
    gemm256<true><<<dim3(3 * Hdim / 128, 4), 256, 0, stream>>>(
        hidden_bf, Hdim, w_hh, Hdim,
        ws_gh4, 3 * Hdim, (size_t)BSZ * 3 * Hdim, 256);

    // 7. GRU elementwise
    gru_kernel<<<dim3(BSZ * Hdim / 256), 256, 0, stream>>>(
        ws_gx4, ws_gh4, b_ih, b_hh, hidden, out_hnew, oc_bf);

    // 8. output projection (split-K x2, 500 blocks) + combine
    outproj512<<<dim3(VOC / 128, 2), 512, 0, stream>>>(
        oc_bf, out_W, ws_op, 1536);
    oproj_comb<<<dim3(BSZ * VOC / 4 / 256), 256, 0, stream>>>(
        ws_op, out_b, out_logits);
}

// Round 5
// 190.040 us; speedup vs baseline: 4.0402x; 1.0078x over previous
//
#include <hip/hip_runtime.h>
#include <math.h>

#define Hdim 1024
#define VOC 32000
#define LSEQ 128
#define BSZ 64

typedef __attribute__((ext_vector_type(8))) short bf16x8;
typedef __attribute__((ext_vector_type(4))) float f32x4;

__device__ __forceinline__ float fast_tanhf(float x) {
    return 1.0f - 2.0f / (__expf(2.0f * x) + 1.0f);
}
__device__ __forceinline__ float sigmoidf(float x) {
    return 1.0f / (1.0f + __expf(-x));
}
__device__ __forceinline__ short f2bf(float f) {
    unsigned u = __float_as_uint(f);
    unsigned r = (u + 0x7fffu + ((u >> 16) & 1u)) >> 16;
    return (short)r;
}

// 16 consecutive f32 -> 16 bf16 at dst (2x 16B stores)
__device__ __forceinline__ void stage16(const float* __restrict__ src, short* dst) {
    f32x4 v0 = *(const f32x4*)(src);
    f32x4 v1 = *(const f32x4*)(src + 4);
    f32x4 v2 = *(const f32x4*)(src + 8);
    f32x4 v3 = *(const f32x4*)(src + 12);
    bf16x8 p0, p1;
    p0[0] = f2bf(v0[0]); p0[1] = f2bf(v0[1]); p0[2] = f2bf(v0[2]); p0[3] = f2bf(v0[3]);
    p0[4] = f2bf(v1[0]); p0[5] = f2bf(v1[1]); p0[6] = f2bf(v1[2]); p0[7] = f2bf(v1[3]);
    p1[0] = f2bf(v2[0]); p1[1] = f2bf(v2[1]); p1[2] = f2bf(v2[2]); p1[3] = f2bf(v2[3]);
    p1[4] = f2bf(v3[0]); p1[5] = f2bf(v3[1]); p1[6] = f2bf(v3[2]); p1[7] = f2bf(v3[3]);
    *(bf16x8*)(dst) = p0;
    *(bf16x8*)(dst + 8) = p1;
}

// ---------------------------------------------------------------------------
// One-pass f32 -> bf16 conversion of enc, attn_W, hidden (grid-stride).
// ---------------------------------------------------------------------------
__global__ __launch_bounds__(256) void convert_bf16(
    const float* __restrict__ enc, const float* __restrict__ attnW,
    const float* __restrict__ hidden,
    short* __restrict__ enc_bf, short* __restrict__ attnW_bf,
    short* __restrict__ hidden_bf)
{
    const int NG_ENC = (LSEQ * BSZ * Hdim) / 8;   // 1048576
    const int NG_AW  = (Hdim * 2 * Hdim) / 8;     // 262144
    const int NG_H   = (BSZ * Hdim) / 8;          // 8192
    const int total = NG_ENC + NG_AW + NG_H;
    for (int g = blockIdx.x * 256 + threadIdx.x; g < total; g += gridDim.x * 256) {
        const float* src; short* dst; int idx;
        if (g < NG_ENC)              { src = enc;    dst = enc_bf;    idx = g; }
        else if (g < NG_ENC + NG_AW) { src = attnW;  dst = attnW_bf;  idx = g - NG_ENC; }
        else                         { src = hidden; dst = hidden_bf; idx = g - NG_ENC - NG_AW; }
        f32x4 a = *(const f32x4*)(src + (size_t)idx * 8);
        f32x4 b = *(const f32x4*)(src + (size_t)idx * 8 + 4);
        bf16x8 p;
        p[0] = f2bf(a[0]); p[1] = f2bf(a[1]); p[2] = f2bf(a[2]); p[3] = f2bf(a[3]);
        p[4] = f2bf(b[0]); p[5] = f2bf(b[1]); p[6] = f2bf(b[2]); p[7] = f2bf(b[3]);
        *(bf16x8*)(dst + (size_t)idx * 8) = p;
    }
}

// ---------------------------------------------------------------------------
// u partial GEMM: u4[s] = hidden_bf @ W2_bf^T  (split-K x4, bf16 operands)
// ---------------------------------------------------------------------------
__global__ __launch_bounds__(256) void ugemm(
    const short* __restrict__ A,    // hidden_bf [64,1024]
    const short* __restrict__ B,    // attnW_bf + Hdim, ld 2048
    float* __restrict__ C)          // [4][64,1024]
{
    __shared__ short As[64 * 72];
    __shared__ short Bs[128 * 72];

    const int t = threadIdx.x;
    const int lane = t & 63, wave = t >> 6;
    const int lr = lane & 15, kh = lane >> 4;
    const int n0 = blockIdx.x * 128;
    const int kstart = blockIdx.y * 256;
    float* Cp = C + (size_t)blockIdx.y * (BSZ * Hdim);

    const int ar = t >> 2, ac = (t & 3) * 16;
    const int br = t >> 1, bc = (t & 1) * 32;

    f32x4 acc[4][2] = {};

    for (int k0 = 0; k0 < 256; k0 += 64) {
        const int kg = kstart + k0;
        {
            const short* s = A + (size_t)ar * Hdim + kg + ac;
            *(bf16x8*)(As + ar * 72 + ac)     = *(const bf16x8*)(s);
            *(bf16x8*)(As + ar * 72 + ac + 8) = *(const bf16x8*)(s + 8);
        }
        {
            const short* s = B + (size_t)(n0 + br) * (2 * Hdim) + kg + bc;
            short* d = Bs + br * 72 + bc;
            *(bf16x8*)(d)      = *(const bf16x8*)(s);
            *(bf16x8*)(d + 8)  = *(const bf16x8*)(s + 8);
            *(bf16x8*)(d + 16) = *(const bf16x8*)(s + 16);
            *(bf16x8*)(d + 24) = *(const bf16x8*)(s + 24);
        }
        __syncthreads();
#pragma unroll
        for (int kk = 0; kk < 64; kk += 32) {
            bf16x8 af[4], bfr[2];
#pragma unroll
            for (int mi = 0; mi < 4; ++mi)
                af[mi] = *(const bf16x8*)(As + (mi * 16 + lr) * 72 + kk + kh * 8);
#pragma unroll
            for (int ni = 0; ni < 2; ++ni)
                bfr[ni] = *(const bf16x8*)(Bs + (wave * 32 + ni * 16 + lr) * 72 + kk + kh * 8);
#pragma unroll
            for (int mi = 0; mi < 4; ++mi)
#pragma unroll
                for (int ni = 0; ni < 2; ++ni)
                    acc[mi][ni] = __builtin_amdgcn_mfma_f32_16x16x32_bf16(
                        af[mi], bfr[ni], acc[mi][ni], 0, 0, 0);
        }
        __syncthreads();
    }

#pragma unroll
    for (int mi = 0; mi < 4; ++mi)
#pragma unroll
        for (int ni = 0; ni < 2; ++ni) {
            const int col = n0 + wave * 32 + ni * 16 + lr;
#pragma unroll
            for (int r = 0; r < 4; ++r) {
                const int row = mi * 16 + kh * 4 + r;
                Cp[(size_t)row * Hdim + col] = acc[mi][ni][r];
            }
        }
}

// ---------------------------------------------------------------------------
// Fused attention scores, 128x128 tile, 512 threads = 8 waves (2x4).
// u-combine fused: u_lds[b][hl] = sum_s u4[s][b][n0+hl] + attnb[n0+hl].
// ---------------------------------------------------------------------------
__global__ __launch_bounds__(512) void attn_scores_mfma(
    const short* __restrict__ enc_bf,   // [8192, 1024]
    const short* __restrict__ W1_bf,    // ld 2048, cols [0,1024)
    const float* __restrict__ u4,       // [4][64, 1024]
    const float* __restrict__ attnb,    // [1024]
    const float* __restrict__ vvec,     // [1024]
    float* __restrict__ scores_part)    // [8][8192]
{
    __shared__ short As[128 * 72];
    __shared__ short Bs[128 * 72];
    __shared__ float red[8][64];
    __shared__ float u_lds[64 * 128];

    const int t = threadIdx.x;
    const int lane = t & 63, wave = t >> 6;     // 8 waves
    const int wr = wave >> 2, wc = wave & 3;    // 2 x 4 wave grid
    const int lr = lane & 15, kh = lane >> 4;
    const int m0 = blockIdx.x * 128;
    const int n0 = blockIdx.y * 128;

    const int srow = t >> 2, scol = (t & 3) * 16;

    // stage u-sum table for this block's 128 h-cols (covered by first sync)
    for (int i = t; i < 64 * 128; i += 512) {
        const int b = i >> 7, hl = i & 127;
        const size_t g = (size_t)b * Hdim + n0 + hl;
        u_lds[i] = u4[g] + u4[65536 + g] + u4[2 * 65536 + g] + u4[3 * 65536 + g]
                 + attnb[n0 + hl];
    }

    f32x4 acc[4][2] = {};

    for (int kg = 0; kg < Hdim; kg += 64) {
        {
            const short* s = enc_bf + (size_t)(m0 + srow) * Hdim + kg + scol;
            *(bf16x8*)(As + srow * 72 + scol)     = *(const bf16x8*)(s);
            *(bf16x8*)(As + srow * 72 + scol + 8) = *(const bf16x8*)(s + 8);
        }
        {
            const short* s = W1_bf + (size_t)(n0 + srow) * (2 * Hdim) + kg + scol;
            *(bf16x8*)(Bs + srow * 72 + scol)     = *(const bf16x8*)(s);
            *(bf16x8*)(Bs + srow * 72 + scol + 8) = *(const bf16x8*)(s + 8);
        }
        __syncthreads();
#pragma unroll
        for (int kk = 0; kk < 64; kk += 32) {
            bf16x8 af[4], bfr[2];
#pragma unroll
            for (int mi = 0; mi < 4; ++mi)
                af[mi] = *(const bf16x8*)(As + (wr * 64 + mi * 16 + lr) * 72 + kk + kh * 8);
#pragma unroll
            for (int ni = 0; ni < 2; ++ni)
                bfr[ni] = *(const bf16x8*)(Bs + (wc * 32 + ni * 16 + lr) * 72 + kk + kh * 8);
#pragma unroll
            for (int mi = 0; mi < 4; ++mi)
#pragma unroll
                for (int ni = 0; ni < 2; ++ni)
                    acc[mi][ni] = __builtin_amdgcn_mfma_f32_16x16x32_bf16(
                        af[mi], bfr[ni], acc[mi][ni], 0, 0, 0);
        }
        __syncthreads();
    }

    // epilogue: tanh + v-weight, reduce over this block's 128 h-cols
    float sv[16];
#pragma unroll
    for (int mi = 0; mi < 4; ++mi)
#pragma unroll
        for (int r = 0; r < 4; ++r) {
            const int lrow = mi * 16 + kh * 4 + r;
            const int b = lrow;                    // b independent of wr (m0%64==0)
            float s = 0.0f;
#pragma unroll
            for (int ni = 0; ni < 2; ++ni) {
                const int hl = wc * 32 + ni * 16 + lr;
                const float e = fast_tanhf(acc[mi][ni][r] + u_lds[b * 128 + hl]);
                s += e * vvec[n0 + hl];
            }
            sv[mi * 4 + r] = s;
        }
#pragma unroll
    for (int i = 0; i < 16; ++i) {
#pragma unroll
        for (int d = 1; d < 16; d <<= 1)
            sv[i] += __shfl_xor(sv[i], d, 64);
    }
    if (lr == 0) {
#pragma unroll
        for (int mi = 0; mi < 4; ++mi)
#pragma unroll
            for (int r = 0; r < 4; ++r)
                red[wave][mi * 16 + kh * 4 + r] = sv[mi * 4 + r];
    }
    __syncthreads();
    if (t < 128) {
        const int wrr = t >> 6, lrow = t & 63;
        scores_part[(size_t)blockIdx.y * (LSEQ * BSZ) + m0 + t] =
            red[wrr * 4 + 0][lrow] + red[wrr * 4 + 1][lrow] +
            red[wrr * 4 + 2][lrow] + red[wrr * 4 + 3][lrow];
    }
}

// ---------------------------------------------------------------------------
// Fused softmax (over L) + weighted context + embedding gather. 1 block per b.
// ---------------------------------------------------------------------------
__global__ __launch_bounds__(256) void softmax_weighted(
    const float* __restrict__ sp,       // [8][8192]
    const short* __restrict__ enc_bf,   // [8192, 1024]
    const int* __restrict__ ids,
    const float* __restrict__ emb,
    float* __restrict__ attn_out,       // [B, L]
    short* __restrict__ x_bf,           // [64, 2048]
    short* __restrict__ oc_bf)          // [64, 3072]
{
    const int b = blockIdx.x, t = threadIdx.x;
    __shared__ float aw[LSEQ];
    __shared__ float red[128];

    // embedding gather: 4 elems per thread (independent of softmax)
    {
        const int id = ids[b];
#pragma unroll
        for (int i = 0; i < 4; ++i) {
            const int h = t * 4 + i;
            const short e = f2bf(emb[(size_t)id * Hdim + h]);
            x_bf[(size_t)b * 2048 + h] = e;
            oc_bf[(size_t)b * 3072 + 2048 + h] = e;
        }
    }

    float s = 0.0f;
    if (t < 128) {
#pragma unroll
        for (int g = 0; g < 8; ++g) s += sp[g * (LSEQ * BSZ) + t * 64 + b];
        red[t] = s;
    }
    __syncthreads();
    for (int off = 64; off > 0; off >>= 1) {
        if (t < off) red[t] = fmaxf(red[t], red[t + off]);
        __syncthreads();
    }
    const float mx = red[0];
    __syncthreads();
    float e = 0.0f;
    if (t < 128) { e = __expf(s - mx); red[t] = e; }
    __syncthreads();
    for (int off = 64; off > 0; off >>= 1) {
        if (t < off) red[t] += red[t + off];
        __syncthreads();
    }
    const float inv = 1.0f / red[0];
    if (t < 128) {
        const float p = e * inv;
        aw[t] = p;
        attn_out[(size_t)b * LSEQ + t] = p;
    }
    __syncthreads();

#pragma unroll
    for (int c = 0; c < 2; ++c) {
        const int h = c * 512 + t * 2;
        float a0 = 0.0f, a1 = 0.0f;
        for (int l = 0; l < LSEQ; ++l) {
            const unsigned w = *(const unsigned*)(enc_bf + ((size_t)l * BSZ + b) * Hdim + h);
            const float p = aw[l];
            a0 = fmaf(p, __uint_as_float(w << 16), a0);
            a1 = fmaf(p, __uint_as_float(w & 0xffff0000u), a1);
        }
        const unsigned packed = (unsigned)(unsigned short)f2bf(a0)
                              | ((unsigned)(unsigned short)f2bf(a1) << 16);
        *(unsigned*)(x_bf + (size_t)b * 2048 + 1024 + h) = packed;
        *(unsigned*)(oc_bf + (size_t)b * 3072 + 1024 + h) = packed;
    }
}

// ---------------------------------------------------------------------------
// Merged GRU gate GEMMs: blockIdx.x<24 -> gx (x_bf @ w_ih^T), else gh
// (hidden_bf @ w_hh^T). Split-K x4 via blockIdx.y. B operands f32, staged.
// ---------------------------------------------------------------------------
__global__ __launch_bounds__(256) void gxgh_gemm(
    const short* __restrict__ x_bf, const float* __restrict__ w_ih,
    const short* __restrict__ hidden_bf, const float* __restrict__ w_hh,
    float* __restrict__ gx4, float* __restrict__ gh4)
{
    __shared__ short As[64 * 72];
    __shared__ short Bs[128 * 72];

    const int t = threadIdx.x;
    const int lane = t & 63, wave = t >> 6;
    const int lr = lane & 15, kh = lane >> 4;

    const short* A; const float* B; float* C; int lda, klen, n0;
    if (blockIdx.x < 24) {
        A = x_bf; B = w_ih; C = gx4; lda = 2048; klen = 512; n0 = blockIdx.x * 128;
    } else {
        A = hidden_bf; B = w_hh; C = gh4; lda = 1024; klen = 256; n0 = (blockIdx.x - 24) * 128;
    }
    const int kstart = blockIdx.y * klen;
    float* Cp = C + (size_t)blockIdx.y * (BSZ * 3 * Hdim);

    const int ar = t >> 2, ac = (t & 3) * 16;
    const int br = t >> 1, bc = (t & 1) * 32;

    f32x4 acc[4][2] = {};

    for (int k0 = 0; k0 < klen; k0 += 64) {
        const int kg = kstart + k0;
        {
            const short* s = A + (size_t)ar * lda + kg + ac;
            *(bf16x8*)(As + ar * 72 + ac)     = *(const bf16x8*)(s);
            *(bf16x8*)(As + ar * 72 + ac + 8) = *(const bf16x8*)(s + 8);
        }
        {
            const float* s = B + (size_t)(n0 + br) * lda + kg + bc;
            stage16(s,      Bs + br * 72 + bc);
            stage16(s + 16, Bs + br * 72 + bc + 16);
        }
        __syncthreads();
#pragma unroll
        for (int kk = 0; kk < 64; kk += 32) {
            bf16x8 af[4], bfr[2];
#pragma unroll
            for (int mi = 0; mi < 4; ++mi)
                af[mi] = *(const bf16x8*)(As + (mi * 16 + lr) * 72 + kk + kh * 8);
#pragma unroll
            for (int ni = 0; ni < 2; ++ni)
                bfr[ni] = *(const bf16x8*)(Bs + (wave * 32 + ni * 16 + lr) * 72 + kk + kh * 8);
#pragma unroll
            for (int mi = 0; mi < 4; ++mi)
#pragma unroll
                for (int ni = 0; ni < 2; ++ni)
                    acc[mi][ni] = __builtin_amdgcn_mfma_f32_16x16x32_bf16(
                        af[mi], bfr[ni], acc[mi][ni], 0, 0, 0);
        }
        __syncthreads();
    }

#pragma unroll
    for (int mi = 0; mi < 4; ++mi)
#pragma unroll
        for (int ni = 0; ni < 2; ++ni) {
            const int col = n0 + wave * 32 + ni * 16 + lr;
#pragma unroll
            for (int r = 0; r < 4; ++r) {
                const int row = mi * 16 + kh * 4 + r;
                Cp[(size_t)row * (3 * Hdim) + col] = acc[mi][ni][r];
            }
        }
}

// ---------------------------------------------------------------------------
// GRU elementwise; sums 4 split-K partials + biases; bf16 out_cat write.
// ---------------------------------------------------------------------------
__global__ __launch_bounds__(256) void gru_kernel(
    const float* __restrict__ gx4, const float* __restrict__ gh4,
    const float* __restrict__ b_ih, const float* __restrict__ b_hh,
    const float* __restrict__ h0,
    float* __restrict__ hnew_out, short* __restrict__ oc_bf)
{
    const int idx = blockIdx.x * 256 + threadIdx.x;
    const int b = idx >> 10, h = idx & 1023;
    const size_t g3 = (size_t)b * (3 * Hdim);
    const size_t P = (size_t)BSZ * 3 * Hdim;
    float xr = b_ih[h], xz = b_ih[Hdim + h], xn = b_ih[2 * Hdim + h];
    float hr = b_hh[h], hz = b_hh[Hdim + h], hn = b_hh[2 * Hdim + h];
#pragma unroll
    for (int s = 0; s < 4; ++s) {
        xr += gx4[s * P + g3 + h];
        xz += gx4[s * P + g3 + Hdim + h];
        xn += gx4[s * P + g3 + 2 * Hdim + h];
        hr += gh4[s * P + g3 + h];
        hz += gh4[s * P + g3 + Hdim + h];
        hn += gh4[s * P + g3 + 2 * Hdim + h];
    }
    const float r = sigmoidf(xr + hr);
    const float z = sigmoidf(xz + hz);
    const float n = fast_tanhf(xn + r * hn);
    const float hv = (1.0f - z) * n + z * h0[(size_t)b * Hdim + h];
    hnew_out[(size_t)b * Hdim + h] = hv;
    oc_bf[g3 + h] = f2bf(hv);
}

// ---------------------------------------------------------------------------
// Output projection, direct write: BN=64, 256 thr = 4 waves, full K=3072.
// grid = VOC/64 = 500 blocks (~2/CU). logits = oc_bf @ out_W^T + out_b.
// ---------------------------------------------------------------------------
__global__ __launch_bounds__(256) void outproj_direct(
    const short* __restrict__ A,    // [64, 3072] bf16
    const float* __restrict__ B,    // [32000, 3072] f32
    const float* __restrict__ bias, // [32000]
    float* __restrict__ logits)     // [64, 32000]
{
    __shared__ short As[64 * 72];
    __shared__ short Bs[64 * 72];

    const int t = threadIdx.x;
    const int lane = t & 63, wave = t >> 6;
    const int lr = lane & 15, kh = lane >> 4;
    const int n0 = blockIdx.x * 64;
    const int sr = t >> 2, sc = (t & 3) * 16;

    f32x4 acc[4] = {};

    for (int kg = 0; kg < 3072; kg += 64) {
        {
            const short* s = A + (size_t)sr * 3072 + kg + sc;
            *(bf16x8*)(As + sr * 72 + sc)     = *(const bf16x8*)(s);
            *(bf16x8*)(As + sr * 72 + sc + 8) = *(const bf16x8*)(s + 8);
        }
        stage16(B + (size_t)(n0 + sr) * 3072 + kg + sc, Bs + sr * 72 + sc);
        __syncthreads();
#pragma unroll
        for (int kk = 0; kk < 64; kk += 32) {
            bf16x8 af[4], bfr;
#pragma unroll
            for (int mi = 0; mi < 4; ++mi)
                af[mi] = *(const bf16x8*)(As + (mi * 16 + lr) * 72 + kk + kh * 8);
            bfr = *(const bf16x8*)(Bs + (wave * 16 + lr) * 72 + kk + kh * 8);
#pragma unroll
            for (int mi = 0; mi < 4; ++mi)
                acc[mi] = __builtin_amdgcn_mfma_f32_16x16x32_bf16(af[mi], bfr, acc[mi], 0, 0, 0);
        }
        __syncthreads();
    }

    const int col = n0 + wave * 16 + lr;
    const float bb = bias[col];
#pragma unroll
    for (int mi = 0; mi < 4; ++mi)
#pragma unroll
        for (int r = 0; r < 4; ++r) {
            const int row = mi * 16 + kh * 4 + r;
            logits[(size_t)row * VOC + col] = acc[mi][r] + bb;
        }
}

// ---------------------------------------------------------------------------
extern "C" void kernel_launch(void* const* d_in, const int* in_sizes, int n_in,
                              void* d_out, int out_size, void* d_ws, size_t ws_size,
                              hipStream_t stream)
{
    const int*   ids    = (const int*)d_in[0];
    const float* hidden = (const float*)d_in[1];
    const float* enc    = (const float*)d_in[2];
    const float* emb    = (const float*)d_in[3];
    const float* attnW  = (const float*)d_in[4];
    const float* attnb  = (const float*)d_in[5];
    const float* vvec   = (const float*)d_in[6];
    const float* w_ih   = (const float*)d_in[7];
    const float* w_hh   = (const float*)d_in[8];
    const float* b_ih   = (const float*)d_in[9];
    const float* b_hh   = (const float*)d_in[10];
    const float* out_W  = (const float*)d_in[11];
    const float* out_b  = (const float*)d_in[12];

    float* out        = (float*)d_out;
    float* out_logits = out;
    float* out_hnew   = out + (size_t)BSZ * VOC;
    float* out_attn   = out_hnew + (size_t)BSZ * Hdim;

    float* ws = (float*)d_ws;
    short* enc_bf    = (short*)ws;                        // 4194304 f
    short* attnW_bf  = (short*)(ws + 4194304);            // 1048576 f
    short* hidden_bf = (short*)(ws + 5242880);            // 32768 f
    float* ws_u4  = ws + 5275648;                         // 262144 f
    float* ws_sp  = ws_u4 + 262144;                       // 65536 f
    short* x_bf   = (short*)(ws_sp + 65536);              // 65536 f
    short* oc_bf  = (short*)(ws_sp + 131072);             // 98304 f
    float* ws_gx4 = ws_sp + 229376;                       // 786432 f
    float* ws_gh4 = ws_gx4 + 786432;                      // 786432 f

    // 1. f32 -> bf16 one-pass conversion
    convert_bf16<<<dim3(1024), 256, 0, stream>>>(
        enc, attnW, hidden, enc_bf, attnW_bf, hidden_bf);

    // 2. u partials: hidden_bf @ W2_bf^T (split-K x4, 32 blocks)
    ugemm<<<dim3(Hdim / 128, 4), 256, 0, stream>>>(
        hidden_bf, attnW_bf + Hdim, ws_u4);

    // 3. fused energy GEMM + u-combine + tanh + v-reduction
    attn_scores_mfma<<<dim3(LSEQ / 2, 8), 512, 0, stream>>>(
        enc_bf, attnW_bf, ws_u4, attnb, vvec, ws_sp);

    // 4. softmax + weighted context + embedding
    softmax_weighted<<<dim3(BSZ), 256, 0, stream>>>(
        ws_sp, enc_bf, ids, emb, out_attn, x_bf, oc_bf);

    // 5. merged GRU gate GEMMs (split-K x4, 192 blocks)
    gxgh_gemm<<<dim3(48, 4), 256, 0, stream>>>(
        x_bf, w_ih, hidden_bf, w_hh, ws_gx4, ws_gh4);

    // 6. GRU elementwise
    gru_kernel<<<dim3(BSZ * Hdim / 256), 256, 0, stream>>>(
        ws_gx4, ws_gh4, b_ih, b_hh, hidden, out_hnew, oc_bf);

    // 7. output projection, direct write (500 blocks)
    outproj_direct<<<dim3(VOC / 64), 256, 0, stream>>>(
        oc_bf, out_W, out_b, out_logits);
}